// Round 7
// baseline (169.533 us; speedup 1.0000x reference)
//
#include <hip/hip_runtime.h>
#include <hip/hip_bf16.h>
#include <cstdint>
#include <cstddef>

// ---------------------------------------------------------------------------
// MultiHeadAttention (B=2, S=2048, D=1024, H=16, DK=64), fp32 in/out,
// bf16 MFMA internal compute.
// cvt(2 fused) -> QKV GEMM (one dispatch, grid.z; Q pre-scaled log2e/8;
// V written transposed per head) -> flash attention (32x32x16 MFMA, 32 q-rows
// per wave, QBLK=128, lane-local softmax, defer-max, IN-REGISTER P via
// cvt_pk + shfl_xor(32)) -> O GEMM 64x128 (fp32 out)
// ---------------------------------------------------------------------------

#define B_ 2
#define S_ 2048
#define D_ 1024
#define H_ 16
#define DK_ 64
#define QSCALE 0.1803368801111244f   /* (1/8)*log2(e): softmax in exp2 domain */

typedef __attribute__((ext_vector_type(8))) short bf16x8;
typedef __attribute__((ext_vector_type(4))) float f32x4;
typedef __attribute__((ext_vector_type(16))) float f32x16;
typedef __attribute__((ext_vector_type(4))) unsigned short u16x4;
typedef __attribute__((ext_vector_type(4))) float float4v;
typedef __attribute__((ext_vector_type(2))) unsigned int u32x2;
typedef __attribute__((ext_vector_type(4))) unsigned int u32x4;

__device__ __forceinline__ unsigned short f2bf(float f) {
  unsigned int u = __float_as_uint(f);
  u += 0x7FFFu + ((u >> 16) & 1u);
  return (unsigned short)(u >> 16);
}
__device__ __forceinline__ unsigned int cvt_pk_bf16(float lo, float hi) {
  unsigned int r;
  asm("v_cvt_pk_bf16_f32 %0, %1, %2" : "=v"(r) : "v"(lo), "v"(hi));
  return r;
}

// ---------------------------- fp32 -> bf16 converts ------------------------
__global__ __launch_bounds__(256) void cvt3(const float* __restrict__ s0,
                                            const float* __restrict__ s1,
                                            const float* __restrict__ s2,
                                            unsigned short* __restrict__ d0,
                                            unsigned short* __restrict__ d1,
                                            unsigned short* __restrict__ d2) {
  const float* src = blockIdx.y == 0 ? s0 : blockIdx.y == 1 ? s1 : s2;
  unsigned short* dst = blockIdx.y == 0 ? d0 : blockIdx.y == 1 ? d1 : d2;
  int i = blockIdx.x * 256 + threadIdx.x;
  float4v v = *(const float4v*)(src + (size_t)i * 4);
  u16x4 o;
  o[0] = f2bf(v[0]); o[1] = f2bf(v[1]); o[2] = f2bf(v[2]); o[3] = f2bf(v[3]);
  *(u16x4*)(dst + (size_t)i * 4) = o;
}

__global__ __launch_bounds__(256) void cvt4(const float* __restrict__ s0,
                                            const float* __restrict__ s1,
                                            const float* __restrict__ s2,
                                            const float* __restrict__ s3,
                                            unsigned short* __restrict__ d0,
                                            unsigned short* __restrict__ d1,
                                            unsigned short* __restrict__ d2,
                                            unsigned short* __restrict__ d3) {
  int z = blockIdx.y;
  const float* src = z == 0 ? s0 : z == 1 ? s1 : z == 2 ? s2 : s3;
  unsigned short* dst = z == 0 ? d0 : z == 1 ? d1 : z == 2 ? d2 : d3;
  int i = blockIdx.x * 256 + threadIdx.x;
  float4v v = *(const float4v*)(src + (size_t)i * 4);
  u16x4 o;
  o[0] = f2bf(v[0]); o[1] = f2bf(v[1]); o[2] = f2bf(v[2]); o[3] = f2bf(v[3]);
  *(u16x4*)(dst + (size_t)i * 4) = o;
}

// ---------------------------- fused QKV GEMM -------------------------------
__global__ __launch_bounds__(256) void gemm_qkv(
    const unsigned short* __restrict__ Xq, const unsigned short* __restrict__ Xk,
    const unsigned short* __restrict__ Xv, const unsigned short* __restrict__ Wq,
    const unsigned short* __restrict__ Wk, const unsigned short* __restrict__ Wv,
    const float* __restrict__ bq, const float* __restrict__ bk,
    const float* __restrict__ bv, unsigned short* __restrict__ Qp,
    unsigned short* __restrict__ Kp, unsigned short* __restrict__ Vt) {
  const int z = blockIdx.z;
  const unsigned short* A = z == 0 ? Xq : z == 1 ? Xk : Xv;
  const unsigned short* W = z == 0 ? Wq : z == 1 ? Wk : Wv;
  const float* bias = z == 0 ? bq : z == 1 ? bk : bv;
  const int K = D_, N = D_;

  __shared__ __align__(16) unsigned short As[128 * 64];
  __shared__ __align__(16) unsigned short Bs[128 * 64];
  const int tid  = threadIdx.x;
  const int lane = tid & 63;
  const int m0 = blockIdx.x * 128;
  const int n0 = blockIdx.y * 128;
  const int wr = ((tid >> 6) >> 1) * 64;
  const int wc = ((tid >> 6) & 1) * 64;
  const int lr = lane & 15;
  const int lk = (lane >> 4) * 8;
  f32x4 acc[4][4] = {};

  const int chunkrow = tid >> 3;
  const int chunkcol = (tid & 7) * 8;

  for (int k0 = 0; k0 < K; k0 += 64) {
    __syncthreads();
#pragma unroll
    for (int i = 0; i < 4; ++i) {
      int row = chunkrow + i * 32;
      const unsigned short* gA = A + (size_t)(m0 + row) * K + k0 + chunkcol;
      const unsigned short* gB = W + (size_t)(n0 + row) * K + k0 + chunkcol;
      __builtin_amdgcn_global_load_lds((const __attribute__((address_space(1))) void*)gA,
          (__attribute__((address_space(3))) void*)(As + row * 64 + chunkcol), 16, 0, 0);
      __builtin_amdgcn_global_load_lds((const __attribute__((address_space(1))) void*)gB,
          (__attribute__((address_space(3))) void*)(Bs + row * 64 + chunkcol), 16, 0, 0);
    }
    __syncthreads();
#pragma unroll
    for (int kk = 0; kk < 2; ++kk) {
      bf16x8 a[4], b[4];
#pragma unroll
      for (int m = 0; m < 4; ++m)
        a[m] = *(const bf16x8*)(As + (wr + m * 16 + lr) * 64 + kk * 32 + lk);
#pragma unroll
      for (int n = 0; n < 4; ++n)
        b[n] = *(const bf16x8*)(Bs + (wc + n * 16 + lr) * 64 + kk * 32 + lk);
#pragma unroll
      for (int m = 0; m < 4; ++m)
#pragma unroll
        for (int n = 0; n < 4; ++n)
          acc[m][n] = __builtin_amdgcn_mfma_f32_16x16x32_bf16(a[m], b[n], acc[m][n], 0, 0, 0);
    }
  }

  const int rbase = (lane >> 4) * 4;
  if (z == 2) {
#pragma unroll
    for (int m = 0; m < 4; ++m)
#pragma unroll
      for (int n = 0; n < 4; ++n) {
        int col = n0 + wc + n * 16 + lr;
        float bvv = bias[col];
        int row0 = m0 + wr + m * 16 + rbase;
        int bb = row0 >> 11, s = row0 & 2047;
        int h = col >> 6, dk = col & 63;
        u16x4 o;
#pragma unroll
        for (int r = 0; r < 4; ++r) o[r] = f2bf(acc[m][n][r] + bvv);
        size_t idx = (((size_t)bb * H_ + h) * DK_ + dk) * S_ + s;
        *(u16x4*)(Vt + idx) = o;
      }
  } else {
    unsigned short* Cout = z == 0 ? Qp : Kp;
    const float scale = z == 0 ? QSCALE : 1.0f;
#pragma unroll
    for (int m = 0; m < 4; ++m)
#pragma unroll
      for (int n = 0; n < 4; ++n) {
        int col = n0 + wc + n * 16 + lr;
        float bvv = bias[col];
#pragma unroll
        for (int r = 0; r < 4; ++r) {
          int row = m0 + wr + m * 16 + rbase + r;
          Cout[(size_t)row * N + col] = f2bf((acc[m][n][r] + bvv) * scale);
        }
      }
  }
}

// ---------------------------- O GEMM (64x128 tile) -------------------------
__global__ __launch_bounds__(256) void gemm_o(const unsigned short* __restrict__ A,
                                              const unsigned short* __restrict__ W,
                                              const float* __restrict__ bias,
                                              float* __restrict__ C,
                                              int M, int N, int K) {
  __shared__ __align__(16) unsigned short As[64 * 64];
  __shared__ __align__(16) unsigned short Bs[128 * 64];
  const int tid  = threadIdx.x;
  const int lane = tid & 63;
  const int m0 = blockIdx.x * 64;
  const int n0 = blockIdx.y * 128;
  const int wr = ((tid >> 6) >> 1) * 32;
  const int wc = ((tid >> 6) & 1) * 64;
  const int lr = lane & 15;
  const int lk = (lane >> 4) * 8;
  f32x4 acc[2][4] = {};

  const int chunkrow = tid >> 3;
  const int chunkcol = (tid & 7) * 8;

  for (int k0 = 0; k0 < K; k0 += 64) {
    __syncthreads();
#pragma unroll
    for (int i = 0; i < 2; ++i) {
      int row = chunkrow + i * 32;
      const unsigned short* gA = A + (size_t)(m0 + row) * K + k0 + chunkcol;
      __builtin_amdgcn_global_load_lds((const __attribute__((address_space(1))) void*)gA,
          (__attribute__((address_space(3))) void*)(As + row * 64 + chunkcol), 16, 0, 0);
    }
#pragma unroll
    for (int i = 0; i < 4; ++i) {
      int row = chunkrow + i * 32;
      const unsigned short* gB = W + (size_t)(n0 + row) * K + k0 + chunkcol;
      __builtin_amdgcn_global_load_lds((const __attribute__((address_space(1))) void*)gB,
          (__attribute__((address_space(3))) void*)(Bs + row * 64 + chunkcol), 16, 0, 0);
    }
    __syncthreads();
#pragma unroll
    for (int kk = 0; kk < 2; ++kk) {
      bf16x8 a[2], b[4];
#pragma unroll
      for (int m = 0; m < 2; ++m)
        a[m] = *(const bf16x8*)(As + (wr + m * 16 + lr) * 64 + kk * 32 + lk);
#pragma unroll
      for (int n = 0; n < 4; ++n)
        b[n] = *(const bf16x8*)(Bs + (wc + n * 16 + lr) * 64 + kk * 32 + lk);
#pragma unroll
      for (int m = 0; m < 2; ++m)
#pragma unroll
        for (int n = 0; n < 4; ++n)
          acc[m][n] = __builtin_amdgcn_mfma_f32_16x16x32_bf16(a[m], b[n], acc[m][n], 0, 0, 0);
    }
  }

  const int rbase = (lane >> 4) * 4;
#pragma unroll
  for (int m = 0; m < 2; ++m)
#pragma unroll
    for (int n = 0; n < 4; ++n) {
      int col = n0 + wc + n * 16 + lr;
      float bvv = bias[col];
#pragma unroll
      for (int r = 0; r < 4; ++r) {
        int row = m0 + wr + m * 16 + rbase + r;
        C[(size_t)row * N + col] = acc[m][n][r] + bvv;
      }
    }
}

// ---------------------------- flash attention ------------------------------
// Grid: (S/128, H, B). 4 waves; wave w owns q rows [q0+32w, +32).
// mfma_f32_32x32x16_bf16, swapped operands:
//   QK: sc = mfma(K_frag, Q_frag) -> D[kv][q], q = lane&31 (lane-local)
//   PV: out = mfma(Vt_frag, P_frag) -> D[d][q]
// P stays in registers: for dest lane (hi5,ql), B-frag dword d of kv-chunk c
// needs cvt_pk(p[8c'+4*hi5+2(d&1)], +1) from lane (d>>1)*32+ql. Each lane
// offers what its partner half needs (select on SOURCE hi5), one
// shfl_xor(32) per pair completes the exchange.
__device__ __forceinline__ bf16x8 lds_read_sw(const unsigned short* base, int row, int col) {
  int P = (row * 64 + col) * 2;
  int X = P ^ ((row & 7) << 4);
  return *(const bf16x8*)((const char*)base + X);
}

__global__ __launch_bounds__(256) void flash_attn(const unsigned short* __restrict__ Qp,
                                                  const unsigned short* __restrict__ Kp,
                                                  const unsigned short* __restrict__ Vtp,
                                                  unsigned short* __restrict__ Op) {
  __shared__ __align__(16) unsigned short Kb[2][4096];   // [kv 64][d 64] swizzled
  __shared__ __align__(16) unsigned short Vb[2][4096];   // [d 64][kv 64] swizzled

  const int tid  = threadIdx.x;
  const int lane = tid & 63;
  const int w = tid >> 6;
  const int bx = blockIdx.x;
  const int qt = (bx & 1) ? (15 - (bx >> 1)) : (bx >> 1);  // causal pairing
  const int q0 = qt * 128;
  const int h  = blockIdx.y;
  const int b  = blockIdx.z;
  const int ql = lane & 31;
  const int hi5 = lane >> 5;
  const int qbase = q0 + w * 32;
  const int qglob = qbase + ql;
  const size_t basebs = (size_t)b * S_ * D_;
  const int hoff = h * DK_;

  // Q B-frag: qf[f] = Q[qglob][hoff + f*16 + hi5*8 .. +8]
  bf16x8 qf[4];
  {
    const unsigned short* qrow = Qp + basebs + (size_t)qglob * D_ + hoff;
#pragma unroll
    for (int f = 0; f < 4; ++f)
      qf[f] = *(const bf16x8*)(qrow + f * 16 + hi5 * 8);
  }

  float m_r = -1e30f;   // running max (log2 domain) for q = qglob
  float l_r = 0.f;
  f32x16 out0 = {};     // d-tile 0: d = (reg&3)+8*(reg>>2)+4*hi5
  f32x16 out1 = {};     // d-tile 1: d = 32 + same

  const unsigned short* gK0 = Kp + basebs + hoff;
  const unsigned short* gV0 = Vtp + ((size_t)b * H_ + h) * DK_ * S_;

  // stage address math hoisted: per-lane dest byte + source element offsets
  int dstX[2], srcK[2], srcV[2];
#pragma unroll
  for (int i = 0; i < 2; ++i) {
    int X = w * 2048 + i * 1024 + (lane) * 16;  // dest byte (linear, lane-ordered)
    int P = X ^ (((X >> 7) & 7) << 4);          // logical byte (pre-swizzled src)
    int row = P >> 7;
    int colu = (P & 127) >> 1;
    dstX[i] = X;
    srcK[i] = row * D_ + colu;
    srcV[i] = row * S_ + colu;
  }

#define STAGE(gK, gV, kb, vb)                                                  \
  {                                                                            \
    _Pragma("unroll")                                                          \
    for (int i = 0; i < 2; ++i) {                                              \
      __builtin_amdgcn_global_load_lds(                                        \
          (const __attribute__((address_space(1))) void*)((gK) + srcK[i]),     \
          (__attribute__((address_space(3))) void*)((char*)(kb) + dstX[i]),    \
          16, 0, 0);                                                           \
      __builtin_amdgcn_global_load_lds(                                        \
          (const __attribute__((address_space(1))) void*)((gV) + srcV[i]),     \
          (__attribute__((address_space(3))) void*)((char*)(vb) + dstX[i]),    \
          16, 0, 0);                                                           \
    }                                                                          \
  }

  const int T = q0 / 64 + 2;
  STAGE(gK0, gV0, Kb[0], Vb[0]);
  __syncthreads();

  for (int t = 0; t < T; ++t) {
    const int cur = t & 1;
    if (t + 1 < T)
      STAGE(gK0 + (size_t)(t + 1) * 64 * D_, gV0 + (t + 1) * 64,
            Kb[cur ^ 1], Vb[cur ^ 1]);

    const int kv0 = t * 64;
    const bool do0 = (kv0 <= qbase);        // subtile kv [kv0, kv0+32) active
    const bool do1 = (kv0 + 32 <= qbase);   // subtile kv [kv0+32, kv0+64) active
    const bool part0 = (kv0 == qbase);      // diagonal -> per-element mask
    const bool part1 = (kv0 + 32 == qbase);

    if (do0) {
      f32x16 sc0 = {}, sc1 = {};
      __builtin_amdgcn_s_setprio(1);
#pragma unroll
      for (int f = 0; f < 4; ++f) {
        bf16x8 kf = lds_read_sw(Kb[cur], ql, f * 16 + hi5 * 8);
        sc0 = __builtin_amdgcn_mfma_f32_32x32x16_bf16(kf, qf[f], sc0, 0, 0, 0);
      }
      if (do1) {
#pragma unroll
        for (int f = 0; f < 4; ++f) {
          bf16x8 kf = lds_read_sw(Kb[cur], 32 + ql, f * 16 + hi5 * 8);
          sc1 = __builtin_amdgcn_mfma_f32_32x32x16_bf16(kf, qf[f], sc1, 0, 0, 0);
        }
      }
      __builtin_amdgcn_s_setprio(0);

      if (part0) {
#pragma unroll
        for (int g = 0; g < 16; ++g) {
          int kvg = kv0 + (g & 3) + 8 * (g >> 2) + 4 * hi5;
          if (kvg > qglob) sc0[g] = -1e30f;
        }
      }
      if (do1 && part1) {
#pragma unroll
        for (int g = 0; g < 16; ++g) {
          int kvg = kv0 + 32 + (g & 3) + 8 * (g >> 2) + 4 * hi5;
          if (kvg > qglob) sc1[g] = -1e30f;
        }
      }

      // row max: local regs + one cross-half shfl
      float pm = sc0[0];
#pragma unroll
      for (int g = 1; g < 16; ++g) pm = fmaxf(pm, sc0[g]);
      if (do1) {
#pragma unroll
        for (int g = 0; g < 16; ++g) pm = fmaxf(pm, sc1[g]);
      }
      pm = fmaxf(pm, __shfl_xor(pm, 32));

      // defer-max: rescale only when running max grew by > 8 (2^8 headroom)
      if (!__all(pm - m_r <= 8.0f)) {
        float mnew = fmaxf(m_r, pm);
        float scl = __builtin_exp2f(m_r - mnew);
        l_r *= scl;
#pragma unroll
        for (int g = 0; g < 16; ++g) { out0[g] *= scl; out1[g] *= scl; }
        m_r = mnew;
      }

      // P = exp2(sc - m_r) in-register -> redistribute -> PV, per 16-kv chunk
      float l_add = 0.f;
#define PV_CHUNK(SVEC, HALF, C)                                                \
      {                                                                        \
        const int g0 = (HALF) * 8;                                             \
        float p0 = __builtin_exp2f((SVEC)[g0 + 0] - m_r);                      \
        float p1 = __builtin_exp2f((SVEC)[g0 + 1] - m_r);                      \
        float p2 = __builtin_exp2f((SVEC)[g0 + 2] - m_r);                      \
        float p3 = __builtin_exp2f((SVEC)[g0 + 3] - m_r);                      \
        float p4 = __builtin_exp2f((SVEC)[g0 + 4] - m_r);                      \
        float p5 = __builtin_exp2f((SVEC)[g0 + 5] - m_r);                      \
        float p6 = __builtin_exp2f((SVEC)[g0 + 6] - m_r);                      \
        float p7 = __builtin_exp2f((SVEC)[g0 + 7] - m_r);                      \
        l_add += ((p0 + p1) + (p2 + p3)) + ((p4 + p5) + (p6 + p7));            \
        unsigned int u0 = cvt_pk_bf16(p0, p1);                                 \
        unsigned int u1 = cvt_pk_bf16(p2, p3);                                 \
        unsigned int u2 = cvt_pk_bf16(p4, p5);                                 \
        unsigned int u3 = cvt_pk_bf16(p6, p7);                                 \
        unsigned int ta = hi5 ? u0 : u2, tb = hi5 ? u1 : u3;                   \
        unsigned int ra = (unsigned int)__shfl_xor((int)ta, 32);               \
        unsigned int rb = (unsigned int)__shfl_xor((int)tb, 32);               \
        u32x4 pw = {hi5 ? ra : u0, hi5 ? rb : u1, hi5 ? u2 : ra, hi5 ? u3 : rb};\
        bf16x8 pf = __builtin_bit_cast(bf16x8, pw);                            \
        bf16x8 vf0 = lds_read_sw(Vb[cur], ql, (C) * 16 + hi5 * 8);             \
        out0 = __builtin_amdgcn_mfma_f32_32x32x16_bf16(vf0, pf, out0, 0, 0, 0);\
        bf16x8 vf1 = lds_read_sw(Vb[cur], 32 + ql, (C) * 16 + hi5 * 8);        \
        out1 = __builtin_amdgcn_mfma_f32_32x32x16_bf16(vf1, pf, out1, 0, 0, 0);\
      }
      __builtin_amdgcn_s_setprio(1);
      PV_CHUNK(sc0, 0, 0);
      PV_CHUNK(sc0, 1, 1);
      if (do1) {
        PV_CHUNK(sc1, 0, 2);
        PV_CHUNK(sc1, 1, 3);
      }
      __builtin_amdgcn_s_setprio(0);
#undef PV_CHUNK

      l_add += __shfl_xor(l_add, 32);
      l_r += l_add;
    }
    __syncthreads();
  }

  // normalize + store: O[qglob][hoff + dt*32 + 8i + 4*hi5 + {0..3}]
  float rcp = 1.0f / l_r;
  unsigned short* orow = Op + basebs + (size_t)qglob * D_ + hoff;
#pragma unroll
  for (int i = 0; i < 4; ++i) {
    u32x2 o0 = {cvt_pk_bf16(out0[4 * i + 0] * rcp, out0[4 * i + 1] * rcp),
                cvt_pk_bf16(out0[4 * i + 2] * rcp, out0[4 * i + 3] * rcp)};
    *(u32x2*)(orow + 8 * i + 4 * hi5) = o0;
    u32x2 o1 = {cvt_pk_bf16(out1[4 * i + 0] * rcp, out1[4 * i + 1] * rcp),
                cvt_pk_bf16(out1[4 * i + 2] * rcp, out1[4 * i + 3] * rcp)};
    *(u32x2*)(orow + 32 + 8 * i + 4 * hi5) = o1;
  }
#undef STAGE
}

// ---------------------------- launch ---------------------------------------
extern "C" void kernel_launch(void* const* d_in, const int* in_sizes, int n_in,
                              void* d_out, int out_size, void* d_ws, size_t ws_size,
                              hipStream_t stream) {
  const float* q  = (const float*)d_in[0];
  const float* k  = (const float*)d_in[1];
  const float* v  = (const float*)d_in[2];
  // d_in[3] = causal mask (tril) -- semantics hard-coded in flash_attn
  const float* Wq = (const float*)d_in[4];
  const float* bq = (const float*)d_in[5];
  const float* Wk = (const float*)d_in[6];
  const float* bk = (const float*)d_in[7];
  const float* Wv = (const float*)d_in[8];
  const float* bv = (const float*)d_in[9];
  const float* Wo = (const float*)d_in[10];
  const float* bo = (const float*)d_in[11];

  const int MSD = B_ * S_;     // 4096 rows
  unsigned short* ws = (unsigned short*)d_ws;
  unsigned short* Xq  = ws;
  unsigned short* Xk  = Xq  + (size_t)MSD * D_;
  unsigned short* Xv  = Xk  + (size_t)MSD * D_;
  unsigned short* Wqb = Xv  + (size_t)MSD * D_;
  unsigned short* Wkb = Wqb + (size_t)D_ * D_;
  unsigned short* Wvb = Wkb + (size_t)D_ * D_;
  unsigned short* Wob = Wvb + (size_t)D_ * D_;
  unsigned short* Qp  = Wob + (size_t)D_ * D_;
  unsigned short* Kp  = Qp  + (size_t)MSD * D_;
  unsigned short* Vt  = Kp  + (size_t)MSD * D_;   // V^T per head: [b][h][dk][s]
  unsigned short* At  = Vt  + (size_t)MSD * D_;

  const int n4a = MSD * D_ / 4;   // 1048576
  const int n4w = D_ * D_ / 4;    // 262144
  dim3 g3(n4a / 256, 3);
  cvt3<<<g3, 256, 0, stream>>>(q, k, v, Xq, Xk, Xv);
  dim3 g4(n4w / 256, 4);
  cvt4<<<g4, 256, 0, stream>>>(Wq, Wk, Wv, Wo, Wqb, Wkb, Wvb, Wob);

  dim3 gqkv(MSD / 128, D_ / 128, 3);   // (32, 8, 3) = 768 blocks
  gemm_qkv<<<gqkv, 256, 0, stream>>>(Xq, Xk, Xv, Wqb, Wkb, Wvb,
                                     bq, bk, bv, Qp, Kp, Vt);

  dim3 ga(S_ / 128, H_, B_);           // (16, 16, 2) = 512 blocks
  flash_attn<<<ga, 256, 0, stream>>>(Qp, Kp, Vt, At);

  dim3 go(MSD / 64, D_ / 128);         // (64, 8) = 512 blocks
  gemm_o<<<go, 256, 0, stream>>>(At, Wob, bo, (float*)d_out, MSD, D_, D_);
}

// Round 8
// 161.075 us; speedup vs baseline: 1.0525x; 1.0525x over previous
//
#include <hip/hip_runtime.h>
#include <hip/hip_bf16.h>
#include <cstdint>
#include <cstddef>

// ---------------------------------------------------------------------------
// MultiHeadAttention (B=2, S=2048, D=1024, H=16, DK=64), fp32 in/out,
// bf16 MFMA internal compute.
// cvt(2 fused) -> QKV GEMM (grid.z; Q pre-scaled log2e/8; V^T per head)
// -> flash attention: QBLK=64, 4 waves = 2(q-half) x 2(kv-parity) partials,
//    128-kv rounds in single-buffer LDS, in-register P, defer-max,
//    end-of-block partial merge; qt work-scatter for CU balance
// -> O GEMM 64x128 (fp32 out)
// ---------------------------------------------------------------------------

#define B_ 2
#define S_ 2048
#define D_ 1024
#define H_ 16
#define DK_ 64
#define QSCALE 0.1803368801111244f   /* (1/8)*log2(e): softmax in exp2 domain */

typedef __attribute__((ext_vector_type(8))) short bf16x8;
typedef __attribute__((ext_vector_type(4))) float f32x4;
typedef __attribute__((ext_vector_type(16))) float f32x16;
typedef __attribute__((ext_vector_type(4))) unsigned short u16x4;
typedef __attribute__((ext_vector_type(4))) float float4v;
typedef __attribute__((ext_vector_type(2))) unsigned int u32x2;
typedef __attribute__((ext_vector_type(4))) unsigned int u32x4;

__device__ __forceinline__ unsigned short f2bf(float f) {
  unsigned int u = __float_as_uint(f);
  u += 0x7FFFu + ((u >> 16) & 1u);
  return (unsigned short)(u >> 16);
}
__device__ __forceinline__ unsigned int cvt_pk_bf16(float lo, float hi) {
  unsigned int r;
  asm("v_cvt_pk_bf16_f32 %0, %1, %2" : "=v"(r) : "v"(lo), "v"(hi));
  return r;
}

// ---------------------------- fp32 -> bf16 converts ------------------------
__global__ __launch_bounds__(256) void cvt3(const float* __restrict__ s0,
                                            const float* __restrict__ s1,
                                            const float* __restrict__ s2,
                                            unsigned short* __restrict__ d0,
                                            unsigned short* __restrict__ d1,
                                            unsigned short* __restrict__ d2) {
  const float* src = blockIdx.y == 0 ? s0 : blockIdx.y == 1 ? s1 : s2;
  unsigned short* dst = blockIdx.y == 0 ? d0 : blockIdx.y == 1 ? d1 : d2;
  int i = blockIdx.x * 256 + threadIdx.x;
  float4v v = *(const float4v*)(src + (size_t)i * 4);
  u16x4 o;
  o[0] = f2bf(v[0]); o[1] = f2bf(v[1]); o[2] = f2bf(v[2]); o[3] = f2bf(v[3]);
  *(u16x4*)(dst + (size_t)i * 4) = o;
}

__global__ __launch_bounds__(256) void cvt4(const float* __restrict__ s0,
                                            const float* __restrict__ s1,
                                            const float* __restrict__ s2,
                                            const float* __restrict__ s3,
                                            unsigned short* __restrict__ d0,
                                            unsigned short* __restrict__ d1,
                                            unsigned short* __restrict__ d2,
                                            unsigned short* __restrict__ d3) {
  int z = blockIdx.y;
  const float* src = z == 0 ? s0 : z == 1 ? s1 : z == 2 ? s2 : s3;
  unsigned short* dst = z == 0 ? d0 : z == 1 ? d1 : z == 2 ? d2 : d3;
  int i = blockIdx.x * 256 + threadIdx.x;
  float4v v = *(const float4v*)(src + (size_t)i * 4);
  u16x4 o;
  o[0] = f2bf(v[0]); o[1] = f2bf(v[1]); o[2] = f2bf(v[2]); o[3] = f2bf(v[3]);
  *(u16x4*)(dst + (size_t)i * 4) = o;
}

// ---------------------------- fused QKV GEMM -------------------------------
__global__ __launch_bounds__(256) void gemm_qkv(
    const unsigned short* __restrict__ Xq, const unsigned short* __restrict__ Xk,
    const unsigned short* __restrict__ Xv, const unsigned short* __restrict__ Wq,
    const unsigned short* __restrict__ Wk, const unsigned short* __restrict__ Wv,
    const float* __restrict__ bq, const float* __restrict__ bk,
    const float* __restrict__ bv, unsigned short* __restrict__ Qp,
    unsigned short* __restrict__ Kp, unsigned short* __restrict__ Vt) {
  const int z = blockIdx.z;
  const unsigned short* A = z == 0 ? Xq : z == 1 ? Xk : Xv;
  const unsigned short* W = z == 0 ? Wq : z == 1 ? Wk : Wv;
  const float* bias = z == 0 ? bq : z == 1 ? bk : bv;
  const int K = D_, N = D_;

  __shared__ __align__(16) unsigned short As[128 * 64];
  __shared__ __align__(16) unsigned short Bs[128 * 64];
  const int tid  = threadIdx.x;
  const int lane = tid & 63;
  const int m0 = blockIdx.x * 128;
  const int n0 = blockIdx.y * 128;
  const int wr = ((tid >> 6) >> 1) * 64;
  const int wc = ((tid >> 6) & 1) * 64;
  const int lr = lane & 15;
  const int lk = (lane >> 4) * 8;
  f32x4 acc[4][4] = {};

  const int chunkrow = tid >> 3;
  const int chunkcol = (tid & 7) * 8;

  for (int k0 = 0; k0 < K; k0 += 64) {
    __syncthreads();
#pragma unroll
    for (int i = 0; i < 4; ++i) {
      int row = chunkrow + i * 32;
      const unsigned short* gA = A + (size_t)(m0 + row) * K + k0 + chunkcol;
      const unsigned short* gB = W + (size_t)(n0 + row) * K + k0 + chunkcol;
      __builtin_amdgcn_global_load_lds((const __attribute__((address_space(1))) void*)gA,
          (__attribute__((address_space(3))) void*)(As + row * 64 + chunkcol), 16, 0, 0);
      __builtin_amdgcn_global_load_lds((const __attribute__((address_space(1))) void*)gB,
          (__attribute__((address_space(3))) void*)(Bs + row * 64 + chunkcol), 16, 0, 0);
    }
    __syncthreads();
#pragma unroll
    for (int kk = 0; kk < 2; ++kk) {
      bf16x8 a[4], b[4];
#pragma unroll
      for (int m = 0; m < 4; ++m)
        a[m] = *(const bf16x8*)(As + (wr + m * 16 + lr) * 64 + kk * 32 + lk);
#pragma unroll
      for (int n = 0; n < 4; ++n)
        b[n] = *(const bf16x8*)(Bs + (wc + n * 16 + lr) * 64 + kk * 32 + lk);
#pragma unroll
      for (int m = 0; m < 4; ++m)
#pragma unroll
        for (int n = 0; n < 4; ++n)
          acc[m][n] = __builtin_amdgcn_mfma_f32_16x16x32_bf16(a[m], b[n], acc[m][n], 0, 0, 0);
    }
  }

  const int rbase = (lane >> 4) * 4;
  if (z == 2) {
#pragma unroll
    for (int m = 0; m < 4; ++m)
#pragma unroll
      for (int n = 0; n < 4; ++n) {
        int col = n0 + wc + n * 16 + lr;
        float bvv = bias[col];
        int row0 = m0 + wr + m * 16 + rbase;
        int bb = row0 >> 11, s = row0 & 2047;
        int h = col >> 6, dk = col & 63;
        u16x4 o;
#pragma unroll
        for (int r = 0; r < 4; ++r) o[r] = f2bf(acc[m][n][r] + bvv);
        size_t idx = (((size_t)bb * H_ + h) * DK_ + dk) * S_ + s;
        *(u16x4*)(Vt + idx) = o;
      }
  } else {
    unsigned short* Cout = z == 0 ? Qp : Kp;
    const float scale = z == 0 ? QSCALE : 1.0f;
#pragma unroll
    for (int m = 0; m < 4; ++m)
#pragma unroll
      for (int n = 0; n < 4; ++n) {
        int col = n0 + wc + n * 16 + lr;
        float bvv = bias[col];
#pragma unroll
        for (int r = 0; r < 4; ++r) {
          int row = m0 + wr + m * 16 + rbase + r;
          Cout[(size_t)row * N + col] = f2bf((acc[m][n][r] + bvv) * scale);
        }
      }
  }
}

// ---------------------------- O GEMM (64x128 tile) -------------------------
__global__ __launch_bounds__(256) void gemm_o(const unsigned short* __restrict__ A,
                                              const unsigned short* __restrict__ W,
                                              const float* __restrict__ bias,
                                              float* __restrict__ C,
                                              int M, int N, int K) {
  __shared__ __align__(16) unsigned short As[64 * 64];
  __shared__ __align__(16) unsigned short Bs[128 * 64];
  const int tid  = threadIdx.x;
  const int lane = tid & 63;
  const int m0 = blockIdx.x * 64;
  const int n0 = blockIdx.y * 128;
  const int wr = ((tid >> 6) >> 1) * 32;
  const int wc = ((tid >> 6) & 1) * 64;
  const int lr = lane & 15;
  const int lk = (lane >> 4) * 8;
  f32x4 acc[2][4] = {};

  const int chunkrow = tid >> 3;
  const int chunkcol = (tid & 7) * 8;

  for (int k0 = 0; k0 < K; k0 += 64) {
    __syncthreads();
#pragma unroll
    for (int i = 0; i < 2; ++i) {
      int row = chunkrow + i * 32;
      const unsigned short* gA = A + (size_t)(m0 + row) * K + k0 + chunkcol;
      __builtin_amdgcn_global_load_lds((const __attribute__((address_space(1))) void*)gA,
          (__attribute__((address_space(3))) void*)(As + row * 64 + chunkcol), 16, 0, 0);
    }
#pragma unroll
    for (int i = 0; i < 4; ++i) {
      int row = chunkrow + i * 32;
      const unsigned short* gB = W + (size_t)(n0 + row) * K + k0 + chunkcol;
      __builtin_amdgcn_global_load_lds((const __attribute__((address_space(1))) void*)gB,
          (__attribute__((address_space(3))) void*)(Bs + row * 64 + chunkcol), 16, 0, 0);
    }
    __syncthreads();
#pragma unroll
    for (int kk = 0; kk < 2; ++kk) {
      bf16x8 a[2], b[4];
#pragma unroll
      for (int m = 0; m < 2; ++m)
        a[m] = *(const bf16x8*)(As + (wr + m * 16 + lr) * 64 + kk * 32 + lk);
#pragma unroll
      for (int n = 0; n < 4; ++n)
        b[n] = *(const bf16x8*)(Bs + (wc + n * 16 + lr) * 64 + kk * 32 + lk);
#pragma unroll
      for (int m = 0; m < 2; ++m)
#pragma unroll
        for (int n = 0; n < 4; ++n)
          acc[m][n] = __builtin_amdgcn_mfma_f32_16x16x32_bf16(a[m], b[n], acc[m][n], 0, 0, 0);
    }
  }

  const int rbase = (lane >> 4) * 4;
#pragma unroll
  for (int m = 0; m < 2; ++m)
#pragma unroll
    for (int n = 0; n < 4; ++n) {
      int col = n0 + wc + n * 16 + lr;
      float bvv = bias[col];
#pragma unroll
      for (int r = 0; r < 4; ++r) {
        int row = m0 + wr + m * 16 + rbase + r;
        C[(size_t)row * N + col] = acc[m][n][r] + bvv;
      }
    }
}

// ---------------------------- flash attention ------------------------------
// Grid: (S/64, H, B). 4 waves: wave w -> q-half qh=w&1 (32 rows), kv-parity
// kp=w>>1. Rounds of 128 kv staged in single-buffer LDS; wave computes its
// 64-kv half per round as an independent flash partial (m,l,out). Partials
// merged across kv-parity at the end via LDS scratch (exact rescale).
__device__ __forceinline__ bf16x8 lds_read_swK(const unsigned short* base, int row, int col) {
  int P = (row * 64 + col) * 2;
  int X = P ^ ((row & 7) << 4);
  return *(const bf16x8*)((const char*)base + X);
}
__device__ __forceinline__ bf16x8 lds_read_swV(const unsigned short* base, int row, int col) {
  int P = (row * 128 + col) * 2;
  int X = P ^ ((row & 7) << 4);
  return *(const bf16x8*)((const char*)base + X);
}

__global__ __launch_bounds__(256) void flash_attn(const unsigned short* __restrict__ Qp,
                                                  const unsigned short* __restrict__ Kp,
                                                  const unsigned short* __restrict__ Vtp,
                                                  unsigned short* __restrict__ Op) {
  // Kb: [kv 128][d 64] swizzled; Vb: [d 64][kv 128] swizzled. 32 KB total;
  // reused as merge scratch after the kv loop.
  __shared__ __align__(16) unsigned short smem[128 * 64 + 64 * 128];
  unsigned short* Kb = smem;
  unsigned short* Vb = smem + 128 * 64;

  const int tid  = threadIdx.x;
  const int lane = tid & 63;
  const int w = tid >> 6;
  const int qh = w & 1;         // q half (32 rows)
  const int kp = w >> 1;        // kv parity (which 64 of the 128-round)
  const int h  = blockIdx.y;
  const int b  = blockIdx.z;
  // work-scatter: balance heavy/light q-tiles across CUs (bijective per h,b)
  const int qt = (blockIdx.x + 4 * (h & 7) + 8 * (h >> 3) + 16 * b) & 31;
  const int q0 = qt * 64;
  const int ql = lane & 31;
  const int hi5 = lane >> 5;
  const int qbase = q0 + qh * 32;
  const int qglob = qbase + ql;
  const size_t basebs = (size_t)b * S_ * D_;
  const int hoff = h * DK_;

  // Q B-frag: qf[f] = Q[qglob][hoff + f*16 + hi5*8 .. +8]
  bf16x8 qf[4];
  {
    const unsigned short* qrow = Qp + basebs + (size_t)qglob * D_ + hoff;
#pragma unroll
    for (int f = 0; f < 4; ++f)
      qf[f] = *(const bf16x8*)(qrow + f * 16 + hi5 * 8);
  }

  float m_r = -1e30f;   // running max (log2 domain), partial for q = qglob
  float l_r = 0.f;
  f32x16 out0 = {};     // d-tile 0: d = (reg&3)+8*(reg>>2)+4*hi5
  f32x16 out1 = {};     // d-tile 1: d = 32 + same

  const unsigned short* gK0 = Kp + basebs + hoff;
  const unsigned short* gV0 = Vtp + ((size_t)b * H_ + h) * DK_ * S_;

  // staging address math (hoisted): 4 chunks of 16B per thread per tensor
  int dstXK[4], srcK[4], dstXV[4], srcV[4];
#pragma unroll
  for (int i = 0; i < 4; ++i) {
    int X = tid * 16 + i * 4096;
    int Pk = X ^ (((X >> 7) & 7) << 4);          // K: 128B rows
    dstXK[i] = X;
    srcK[i] = (Pk >> 7) * D_ + ((Pk & 127) >> 1);
    int Pv = X ^ (((X >> 8) & 7) << 4);          // V: 256B rows
    dstXV[i] = X;
    srcV[i] = (Pv >> 8) * S_ + ((Pv & 255) >> 1);
  }

  const int R = (qt + 2) >> 1;   // rounds of 128 kv

  for (int r = 0; r < R; ++r) {
    __syncthreads();   // previous round's consumers done; buffer free
    {
      const unsigned short* gK = gK0 + (size_t)(r * 128) * D_;
      const unsigned short* gV = gV0 + r * 128;
#pragma unroll
      for (int i = 0; i < 4; ++i) {
        __builtin_amdgcn_global_load_lds(
            (const __attribute__((address_space(1))) void*)(gK + srcK[i]),
            (__attribute__((address_space(3))) void*)((char*)Kb + dstXK[i]), 16, 0, 0);
        __builtin_amdgcn_global_load_lds(
            (const __attribute__((address_space(1))) void*)(gV + srcV[i]),
            (__attribute__((address_space(3))) void*)((char*)Vb + dstXV[i]), 16, 0, 0);
      }
    }
    __syncthreads();   // staged (drains vmcnt)

    const int kv0w = r * 128 + kp * 64;     // this wave's 64-kv window
    const bool do0 = (kv0w <= qbase);
    const bool do1 = (kv0w + 32 <= qbase);
    const bool part0 = (kv0w == qbase);
    const bool part1 = (kv0w + 32 == qbase);
    if (!do0) continue;

    f32x16 sc0 = {}, sc1 = {};
    __builtin_amdgcn_s_setprio(1);
#pragma unroll
    for (int f = 0; f < 4; ++f) {
      bf16x8 kf = lds_read_swK(Kb, kp * 64 + ql, f * 16 + hi5 * 8);
      sc0 = __builtin_amdgcn_mfma_f32_32x32x16_bf16(kf, qf[f], sc0, 0, 0, 0);
    }
    if (do1) {
#pragma unroll
      for (int f = 0; f < 4; ++f) {
        bf16x8 kf = lds_read_swK(Kb, kp * 64 + 32 + ql, f * 16 + hi5 * 8);
        sc1 = __builtin_amdgcn_mfma_f32_32x32x16_bf16(kf, qf[f], sc1, 0, 0, 0);
      }
    }
    __builtin_amdgcn_s_setprio(0);

    if (part0) {
#pragma unroll
      for (int g = 0; g < 16; ++g) {
        int kvg = kv0w + (g & 3) + 8 * (g >> 2) + 4 * hi5;
        if (kvg > qglob) sc0[g] = -1e30f;
      }
    }
    if (do1 && part1) {
#pragma unroll
      for (int g = 0; g < 16; ++g) {
        int kvg = kv0w + 32 + (g & 3) + 8 * (g >> 2) + 4 * hi5;
        if (kvg > qglob) sc1[g] = -1e30f;
      }
    }

    // row max (lane-local regs + one cross-half shfl)
    float pm = sc0[0];
#pragma unroll
    for (int g = 1; g < 16; ++g) pm = fmaxf(pm, sc0[g]);
    if (do1) {
#pragma unroll
      for (int g = 0; g < 16; ++g) pm = fmaxf(pm, sc1[g]);
    }
    pm = fmaxf(pm, __shfl_xor(pm, 32));

    // defer-max: rescale only when running max grew by > 8 (2^8 headroom)
    if (!__all(pm - m_r <= 8.0f)) {
      float mnew = fmaxf(m_r, pm);
      float scl = __builtin_exp2f(m_r - mnew);
      l_r *= scl;
#pragma unroll
      for (int g = 0; g < 16; ++g) { out0[g] *= scl; out1[g] *= scl; }
      m_r = mnew;
    }

    // P = exp2(sc - m_r) in-register -> redistribute -> PV, per 16-kv chunk
    float l_add = 0.f;
#define PV_CHUNK(SVEC, HALF, C)                                                \
    {                                                                          \
      const int g0 = (HALF) * 8;                                               \
      float p0 = __builtin_exp2f((SVEC)[g0 + 0] - m_r);                        \
      float p1 = __builtin_exp2f((SVEC)[g0 + 1] - m_r);                        \
      float p2 = __builtin_exp2f((SVEC)[g0 + 2] - m_r);                        \
      float p3 = __builtin_exp2f((SVEC)[g0 + 3] - m_r);                        \
      float p4 = __builtin_exp2f((SVEC)[g0 + 4] - m_r);                        \
      float p5 = __builtin_exp2f((SVEC)[g0 + 5] - m_r);                        \
      float p6 = __builtin_exp2f((SVEC)[g0 + 6] - m_r);                        \
      float p7 = __builtin_exp2f((SVEC)[g0 + 7] - m_r);                        \
      l_add += ((p0 + p1) + (p2 + p3)) + ((p4 + p5) + (p6 + p7));              \
      unsigned int u0 = cvt_pk_bf16(p0, p1);                                   \
      unsigned int u1 = cvt_pk_bf16(p2, p3);                                   \
      unsigned int u2 = cvt_pk_bf16(p4, p5);                                   \
      unsigned int u3 = cvt_pk_bf16(p6, p7);                                   \
      unsigned int ta = hi5 ? u0 : u2, tb = hi5 ? u1 : u3;                     \
      unsigned int ra = (unsigned int)__shfl_xor((int)ta, 32);                 \
      unsigned int rb = (unsigned int)__shfl_xor((int)tb, 32);                 \
      u32x4 pw = {hi5 ? ra : u0, hi5 ? rb : u1, hi5 ? u2 : ra, hi5 ? u3 : rb}; \
      bf16x8 pf = __builtin_bit_cast(bf16x8, pw);                              \
      bf16x8 vf0 = lds_read_swV(Vb, ql, kp * 64 + (C) * 16 + hi5 * 8);         \
      out0 = __builtin_amdgcn_mfma_f32_32x32x16_bf16(vf0, pf, out0, 0, 0, 0);  \
      bf16x8 vf1 = lds_read_swV(Vb, 32 + ql, kp * 64 + (C) * 16 + hi5 * 8);    \
      out1 = __builtin_amdgcn_mfma_f32_32x32x16_bf16(vf1, pf, out1, 0, 0, 0);  \
    }
    __builtin_amdgcn_s_setprio(1);
    PV_CHUNK(sc0, 0, 0);
    PV_CHUNK(sc0, 1, 1);
    if (do1) {
      PV_CHUNK(sc1, 0, 2);
      PV_CHUNK(sc1, 1, 3);
    }
    __builtin_amdgcn_s_setprio(0);
#undef PV_CHUNK

    l_add += __shfl_xor(l_add, 32);
    l_r += l_add;
  }

  // ---- merge partials across kv-parity (scratch overlays K/V buffers) ----
  __syncthreads();
  float* scr = (float*)smem;   // [qh][lane][34]: out0[16], out1[16], m, l
  if (kp == 1) {
    float* p = scr + ((size_t)qh * 64 + lane) * 34;
#pragma unroll
    for (int g = 0; g < 16; ++g) { p[g] = out0[g]; p[16 + g] = out1[g]; }
    p[32] = m_r;
    p[33] = l_r;
  }
  __syncthreads();
  if (kp == 0) {
    const float* p = scr + ((size_t)qh * 64 + lane) * 34;
    float m1 = p[32], l1 = p[33];
    float mM = fmaxf(m_r, m1);
    float s0 = __builtin_exp2f(m_r - mM);
    float s1 = __builtin_exp2f(m1 - mM);
    float rcp = 1.0f / (l_r * s0 + l1 * s1);
    float a0 = s0 * rcp, a1 = s1 * rcp;
    unsigned short* orow = Op + basebs + (size_t)qglob * D_ + hoff;
#pragma unroll
    for (int i = 0; i < 4; ++i) {
      u32x2 o0 = {cvt_pk_bf16(out0[4 * i + 0] * a0 + p[4 * i + 0] * a1,
                              out0[4 * i + 1] * a0 + p[4 * i + 1] * a1),
                  cvt_pk_bf16(out0[4 * i + 2] * a0 + p[4 * i + 2] * a1,
                              out0[4 * i + 3] * a0 + p[4 * i + 3] * a1)};
      *(u32x2*)(orow + 8 * i + 4 * hi5) = o0;
      u32x2 o1 = {cvt_pk_bf16(out1[4 * i + 0] * a0 + p[16 + 4 * i + 0] * a1,
                              out1[4 * i + 1] * a0 + p[16 + 4 * i + 1] * a1),
                  cvt_pk_bf16(out1[4 * i + 2] * a0 + p[16 + 4 * i + 2] * a1,
                              out1[4 * i + 3] * a0 + p[16 + 4 * i + 3] * a1)};
      *(u32x2*)(orow + 32 + 8 * i + 4 * hi5) = o1;
    }
  }
}

// ---------------------------- launch ---------------------------------------
extern "C" void kernel_launch(void* const* d_in, const int* in_sizes, int n_in,
                              void* d_out, int out_size, void* d_ws, size_t ws_size,
                              hipStream_t stream) {
  const float* q  = (const float*)d_in[0];
  const float* k  = (const float*)d_in[1];
  const float* v  = (const float*)d_in[2];
  // d_in[3] = causal mask (tril) -- semantics hard-coded in flash_attn
  const float* Wq = (const float*)d_in[4];
  const float* bq = (const float*)d_in[5];
  const float* Wk = (const float*)d_in[6];
  const float* bk = (const float*)d_in[7];
  const float* Wv = (const float*)d_in[8];
  const float* bv = (const float*)d_in[9];
  const float* Wo = (const float*)d_in[10];
  const float* bo = (const float*)d_in[11];

  const int MSD = B_ * S_;     // 4096 rows
  unsigned short* ws = (unsigned short*)d_ws;
  unsigned short* Xq  = ws;
  unsigned short* Xk  = Xq  + (size_t)MSD * D_;
  unsigned short* Xv  = Xk  + (size_t)MSD * D_;
  unsigned short* Wqb = Xv  + (size_t)MSD * D_;
  unsigned short* Wkb = Wqb + (size_t)D_ * D_;
  unsigned short* Wvb = Wkb + (size_t)D_ * D_;
  unsigned short* Wob = Wvb + (size_t)D_ * D_;
  unsigned short* Qp  = Wob + (size_t)D_ * D_;
  unsigned short* Kp  = Qp  + (size_t)MSD * D_;
  unsigned short* Vt  = Kp  + (size_t)MSD * D_;   // V^T per head: [b][h][dk][s]
  unsigned short* At  = Vt  + (size_t)MSD * D_;

  const int n4a = MSD * D_ / 4;   // 1048576
  const int n4w = D_ * D_ / 4;    // 262144
  dim3 g3(n4a / 256, 3);
  cvt3<<<g3, 256, 0, stream>>>(q, k, v, Xq, Xk, Xv);
  dim3 g4(n4w / 256, 4);
  cvt4<<<g4, 256, 0, stream>>>(Wq, Wk, Wv, Wo, Wqb, Wkb, Wvb, Wob);

  dim3 gqkv(MSD / 128, D_ / 128, 3);   // (32, 8, 3) = 768 blocks
  gemm_qkv<<<gqkv, 256, 0, stream>>>(Xq, Xk, Xv, Wqb, Wkb, Wvb,
                                     bq, bk, bv, Qp, Kp, Vt);

  dim3 ga(S_ / 64, H_, B_);            // (32, 16, 2) = 1024 blocks
  flash_attn<<<ga, 256, 0, stream>>>(Qp, Kp, Vt, At);

  dim3 go(MSD / 64, D_ / 128);         // (64, 8) = 512 blocks
  gemm_o<<<go, 256, 0, stream>>>(At, Wob, bo, (float*)d_out, MSD, D_, D_);
}

// Round 9
// 138.497 us; speedup vs baseline: 1.2241x; 1.1630x over previous
//
#include <hip/hip_runtime.h>
#include <hip/hip_bf16.h>
#include <cstdint>
#include <cstddef>

// ---------------------------------------------------------------------------
// MultiHeadAttention (B=2, S=2048, D=1024, H=16, DK=64), fp32 in/out,
// bf16 MFMA internal compute.
// cvt(2 fused) -> QKV GEMM (grid.z; Q pre-scaled log2e/8; V^T per head)
// -> flash attention: paired q-tiles (bx, 31-bx) per block (uniform 17
//    rounds), 128-kv rounds double-buffered (64KB LDS), 4 waves =
//    2(q-half) x 2(kv-parity) partials, in-register P, defer-max,
//    end-of-tile partial merge via LDS scratch overlay
// -> O GEMM 64x128 (fp32 out)
// ---------------------------------------------------------------------------

#define B_ 2
#define S_ 2048
#define D_ 1024
#define H_ 16
#define DK_ 64
#define QSCALE 0.1803368801111244f   /* (1/8)*log2(e): softmax in exp2 domain */

typedef __attribute__((ext_vector_type(8))) short bf16x8;
typedef __attribute__((ext_vector_type(4))) float f32x4;
typedef __attribute__((ext_vector_type(16))) float f32x16;
typedef __attribute__((ext_vector_type(4))) unsigned short u16x4;
typedef __attribute__((ext_vector_type(4))) float float4v;
typedef __attribute__((ext_vector_type(2))) unsigned int u32x2;
typedef __attribute__((ext_vector_type(4))) unsigned int u32x4;

__device__ __forceinline__ unsigned short f2bf(float f) {
  unsigned int u = __float_as_uint(f);
  u += 0x7FFFu + ((u >> 16) & 1u);
  return (unsigned short)(u >> 16);
}
__device__ __forceinline__ unsigned int cvt_pk_bf16(float lo, float hi) {
  unsigned int r;
  asm("v_cvt_pk_bf16_f32 %0, %1, %2" : "=v"(r) : "v"(lo), "v"(hi));
  return r;
}

// ---------------------------- fp32 -> bf16 converts ------------------------
__global__ __launch_bounds__(256) void cvt3(const float* __restrict__ s0,
                                            const float* __restrict__ s1,
                                            const float* __restrict__ s2,
                                            unsigned short* __restrict__ d0,
                                            unsigned short* __restrict__ d1,
                                            unsigned short* __restrict__ d2) {
  const float* src = blockIdx.y == 0 ? s0 : blockIdx.y == 1 ? s1 : s2;
  unsigned short* dst = blockIdx.y == 0 ? d0 : blockIdx.y == 1 ? d1 : d2;
  int i = blockIdx.x * 256 + threadIdx.x;
  float4v v = *(const float4v*)(src + (size_t)i * 4);
  u16x4 o;
  o[0] = f2bf(v[0]); o[1] = f2bf(v[1]); o[2] = f2bf(v[2]); o[3] = f2bf(v[3]);
  *(u16x4*)(dst + (size_t)i * 4) = o;
}

__global__ __launch_bounds__(256) void cvt4(const float* __restrict__ s0,
                                            const float* __restrict__ s1,
                                            const float* __restrict__ s2,
                                            const float* __restrict__ s3,
                                            unsigned short* __restrict__ d0,
                                            unsigned short* __restrict__ d1,
                                            unsigned short* __restrict__ d2,
                                            unsigned short* __restrict__ d3) {
  int z = blockIdx.y;
  const float* src = z == 0 ? s0 : z == 1 ? s1 : z == 2 ? s2 : s3;
  unsigned short* dst = z == 0 ? d0 : z == 1 ? d1 : z == 2 ? d2 : d3;
  int i = blockIdx.x * 256 + threadIdx.x;
  float4v v = *(const float4v*)(src + (size_t)i * 4);
  u16x4 o;
  o[0] = f2bf(v[0]); o[1] = f2bf(v[1]); o[2] = f2bf(v[2]); o[3] = f2bf(v[3]);
  *(u16x4*)(dst + (size_t)i * 4) = o;
}

// ---------------------------- fused QKV GEMM -------------------------------
__global__ __launch_bounds__(256) void gemm_qkv(
    const unsigned short* __restrict__ Xq, const unsigned short* __restrict__ Xk,
    const unsigned short* __restrict__ Xv, const unsigned short* __restrict__ Wq,
    const unsigned short* __restrict__ Wk, const unsigned short* __restrict__ Wv,
    const float* __restrict__ bq, const float* __restrict__ bk,
    const float* __restrict__ bv, unsigned short* __restrict__ Qp,
    unsigned short* __restrict__ Kp, unsigned short* __restrict__ Vt) {
  const int z = blockIdx.z;
  const unsigned short* A = z == 0 ? Xq : z == 1 ? Xk : Xv;
  const unsigned short* W = z == 0 ? Wq : z == 1 ? Wk : Wv;
  const float* bias = z == 0 ? bq : z == 1 ? bk : bv;
  const int K = D_, N = D_;

  __shared__ __align__(16) unsigned short As[128 * 64];
  __shared__ __align__(16) unsigned short Bs[128 * 64];
  const int tid  = threadIdx.x;
  const int lane = tid & 63;
  const int m0 = blockIdx.x * 128;
  const int n0 = blockIdx.y * 128;
  const int wr = ((tid >> 6) >> 1) * 64;
  const int wc = ((tid >> 6) & 1) * 64;
  const int lr = lane & 15;
  const int lk = (lane >> 4) * 8;
  f32x4 acc[4][4] = {};

  const int chunkrow = tid >> 3;
  const int chunkcol = (tid & 7) * 8;

  for (int k0 = 0; k0 < K; k0 += 64) {
    __syncthreads();
#pragma unroll
    for (int i = 0; i < 4; ++i) {
      int row = chunkrow + i * 32;
      const unsigned short* gA = A + (size_t)(m0 + row) * K + k0 + chunkcol;
      const unsigned short* gB = W + (size_t)(n0 + row) * K + k0 + chunkcol;
      __builtin_amdgcn_global_load_lds((const __attribute__((address_space(1))) void*)gA,
          (__attribute__((address_space(3))) void*)(As + row * 64 + chunkcol), 16, 0, 0);
      __builtin_amdgcn_global_load_lds((const __attribute__((address_space(1))) void*)gB,
          (__attribute__((address_space(3))) void*)(Bs + row * 64 + chunkcol), 16, 0, 0);
    }
    __syncthreads();
#pragma unroll
    for (int kk = 0; kk < 2; ++kk) {
      bf16x8 a[4], b[4];
#pragma unroll
      for (int m = 0; m < 4; ++m)
        a[m] = *(const bf16x8*)(As + (wr + m * 16 + lr) * 64 + kk * 32 + lk);
#pragma unroll
      for (int n = 0; n < 4; ++n)
        b[n] = *(const bf16x8*)(Bs + (wc + n * 16 + lr) * 64 + kk * 32 + lk);
#pragma unroll
      for (int m = 0; m < 4; ++m)
#pragma unroll
        for (int n = 0; n < 4; ++n)
          acc[m][n] = __builtin_amdgcn_mfma_f32_16x16x32_bf16(a[m], b[n], acc[m][n], 0, 0, 0);
    }
  }

  const int rbase = (lane >> 4) * 4;
  if (z == 2) {
#pragma unroll
    for (int m = 0; m < 4; ++m)
#pragma unroll
      for (int n = 0; n < 4; ++n) {
        int col = n0 + wc + n * 16 + lr;
        float bvv = bias[col];
        int row0 = m0 + wr + m * 16 + rbase;
        int bb = row0 >> 11, s = row0 & 2047;
        int h = col >> 6, dk = col & 63;
        u16x4 o;
#pragma unroll
        for (int r = 0; r < 4; ++r) o[r] = f2bf(acc[m][n][r] + bvv);
        size_t idx = (((size_t)bb * H_ + h) * DK_ + dk) * S_ + s;
        *(u16x4*)(Vt + idx) = o;
      }
  } else {
    unsigned short* Cout = z == 0 ? Qp : Kp;
    const float scale = z == 0 ? QSCALE : 1.0f;
#pragma unroll
    for (int m = 0; m < 4; ++m)
#pragma unroll
      for (int n = 0; n < 4; ++n) {
        int col = n0 + wc + n * 16 + lr;
        float bvv = bias[col];
#pragma unroll
        for (int r = 0; r < 4; ++r) {
          int row = m0 + wr + m * 16 + rbase + r;
          Cout[(size_t)row * N + col] = f2bf((acc[m][n][r] + bvv) * scale);
        }
      }
  }
}

// ---------------------------- O GEMM (64x128 tile) -------------------------
__global__ __launch_bounds__(256) void gemm_o(const unsigned short* __restrict__ A,
                                              const unsigned short* __restrict__ W,
                                              const float* __restrict__ bias,
                                              float* __restrict__ C,
                                              int M, int N, int K) {
  __shared__ __align__(16) unsigned short As[64 * 64];
  __shared__ __align__(16) unsigned short Bs[128 * 64];
  const int tid  = threadIdx.x;
  const int lane = tid & 63;
  const int m0 = blockIdx.x * 64;
  const int n0 = blockIdx.y * 128;
  const int wr = ((tid >> 6) >> 1) * 32;
  const int wc = ((tid >> 6) & 1) * 64;
  const int lr = lane & 15;
  const int lk = (lane >> 4) * 8;
  f32x4 acc[2][4] = {};

  const int chunkrow = tid >> 3;
  const int chunkcol = (tid & 7) * 8;

  for (int k0 = 0; k0 < K; k0 += 64) {
    __syncthreads();
#pragma unroll
    for (int i = 0; i < 2; ++i) {
      int row = chunkrow + i * 32;
      const unsigned short* gA = A + (size_t)(m0 + row) * K + k0 + chunkcol;
      __builtin_amdgcn_global_load_lds((const __attribute__((address_space(1))) void*)gA,
          (__attribute__((address_space(3))) void*)(As + row * 64 + chunkcol), 16, 0, 0);
    }
#pragma unroll
    for (int i = 0; i < 4; ++i) {
      int row = chunkrow + i * 32;
      const unsigned short* gB = W + (size_t)(n0 + row) * K + k0 + chunkcol;
      __builtin_amdgcn_global_load_lds((const __attribute__((address_space(1))) void*)gB,
          (__attribute__((address_space(3))) void*)(Bs + row * 64 + chunkcol), 16, 0, 0);
    }
    __syncthreads();
#pragma unroll
    for (int kk = 0; kk < 2; ++kk) {
      bf16x8 a[2], b[4];
#pragma unroll
      for (int m = 0; m < 2; ++m)
        a[m] = *(const bf16x8*)(As + (wr + m * 16 + lr) * 64 + kk * 32 + lk);
#pragma unroll
      for (int n = 0; n < 4; ++n)
        b[n] = *(const bf16x8*)(Bs + (wc + n * 16 + lr) * 64 + kk * 32 + lk);
#pragma unroll
      for (int m = 0; m < 2; ++m)
#pragma unroll
        for (int n = 0; n < 4; ++n)
          acc[m][n] = __builtin_amdgcn_mfma_f32_16x16x32_bf16(a[m], b[n], acc[m][n], 0, 0, 0);
    }
  }

  const int rbase = (lane >> 4) * 4;
#pragma unroll
  for (int m = 0; m < 2; ++m)
#pragma unroll
    for (int n = 0; n < 4; ++n) {
      int col = n0 + wc + n * 16 + lr;
      float bvv = bias[col];
#pragma unroll
      for (int r = 0; r < 4; ++r) {
        int row = m0 + wr + m * 16 + rbase + r;
        C[(size_t)row * N + col] = acc[m][n][r] + bvv;
      }
    }
}

// ---------------------------- flash attention ------------------------------
// Grid: (16, H, B). Block processes q-tiles qtA=31-bx then qtB=bx (uniform
// 17 rounds total). 4 waves: qh=w&1 (32 q rows), kp=w>>1 (64-kv half of each
// 128-kv round). Double-buffered rounds: barrier -> prefetch(r+1) ->
// compute(r) -> barrier. Partials merged across kp via LDS scratch overlay.
__device__ __forceinline__ bf16x8 lds_read_swK(const unsigned short* base, int row, int col) {
  int P = (row * 64 + col) * 2;
  int X = P ^ ((row & 7) << 4);
  return *(const bf16x8*)((const char*)base + X);
}
__device__ __forceinline__ bf16x8 lds_read_swV(const unsigned short* base, int row, int col) {
  int P = (row * 128 + col) * 2;
  int X = P ^ ((row & 7) << 4);
  return *(const bf16x8*)((const char*)base + X);
}

__global__ __launch_bounds__(256) void flash_attn(const unsigned short* __restrict__ Qp,
                                                  const unsigned short* __restrict__ Kp,
                                                  const unsigned short* __restrict__ Vtp,
                                                  unsigned short* __restrict__ Op) {
  // two buffers of (K: 128x64 + V^T: 64x128) bf16 = 32KB each; scratch for
  // the partial-merge overlays buffer 0 (fenced by barriers).
  __shared__ __align__(16) unsigned short smem[32768];

  const int tid  = threadIdx.x;
  const int lane = tid & 63;
  const int w = tid >> 6;
  const int qh = w & 1;         // q half (32 rows)
  const int kp = w >> 1;        // kv parity (which 64 of the 128-round)
  const int h  = blockIdx.y;
  const int b  = blockIdx.z;
  const int ql = lane & 31;
  const int hi5 = lane >> 5;
  const size_t basebs = (size_t)b * S_ * D_;
  const int hoff = h * DK_;

  const unsigned short* gK0 = Kp + basebs + hoff;
  const unsigned short* gV0 = Vtp + ((size_t)b * H_ + h) * DK_ * S_;

  // staging address math (hoisted): 4 chunks of 16B per thread per tensor
  int dstXK[4], srcK[4], srcV[4];
#pragma unroll
  for (int i = 0; i < 4; ++i) {
    int X = tid * 16 + i * 4096;
    int Pk = X ^ (((X >> 7) & 7) << 4);          // K: 128B rows
    dstXK[i] = X;
    srcK[i] = (Pk >> 7) * D_ + ((Pk & 127) >> 1);
    int Pv = X ^ (((X >> 8) & 7) << 4);          // V: 256B rows
    srcV[i] = (Pv >> 8) * S_ + ((Pv & 255) >> 1);
  }

#define STAGE(RR, BUF)                                                         \
  {                                                                            \
    const unsigned short* gK = gK0 + (size_t)((RR) * 128) * D_;                \
    const unsigned short* gV = gV0 + (RR) * 128;                               \
    char* kb = (char*)smem + (BUF) * 32768;                                    \
    char* vb = kb + 16384;                                                     \
    _Pragma("unroll")                                                          \
    for (int i = 0; i < 4; ++i) {                                              \
      __builtin_amdgcn_global_load_lds(                                        \
          (const __attribute__((address_space(1))) void*)(gK + srcK[i]),       \
          (__attribute__((address_space(3))) void*)(kb + dstXK[i]), 16, 0, 0); \
      __builtin_amdgcn_global_load_lds(                                        \
          (const __attribute__((address_space(1))) void*)(gV + srcV[i]),       \
          (__attribute__((address_space(3))) void*)(vb + dstXK[i]), 16, 0, 0); \
    }                                                                          \
  }

  for (int s = 0; s < 2; ++s) {
    const int qt = s == 0 ? 31 - (int)blockIdx.x : (int)blockIdx.x;
    const int q0 = qt * 64;
    const int qbase = q0 + qh * 32;
    const int qglob = qbase + ql;

    // Q B-frag: qf[f] = Q[qglob][hoff + f*16 + hi5*8 .. +8]
    bf16x8 qf[4];
    {
      const unsigned short* qrow = Qp + basebs + (size_t)qglob * D_ + hoff;
#pragma unroll
      for (int f = 0; f < 4; ++f)
        qf[f] = *(const bf16x8*)(qrow + f * 16 + hi5 * 8);
    }

    float m_r = -1e30f;
    float l_r = 0.f;
    f32x16 out0 = {};   // d-tile 0: d = (reg&3)+8*(reg>>2)+4*hi5
    f32x16 out1 = {};   // d-tile 1: d = 32 + same

    const int R = (qt + 2) >> 1;   // rounds of 128 kv

    STAGE(0, 0);
    __syncthreads();               // round 0 staged

    for (int r = 0; r < R; ++r) {
      const int cur = r & 1;
      if (r + 1 < R) STAGE(r + 1, cur ^ 1);   // prefetch, hidden under compute

      const unsigned short* Kb = smem + cur * 16384;
      const unsigned short* Vb = Kb + 8192;

      const int kv0w = r * 128 + kp * 64;
      const bool do0 = (kv0w <= qbase);
      const bool do1 = (kv0w + 32 <= qbase);
      const bool part0 = (kv0w == qbase);
      const bool part1 = (kv0w + 32 == qbase);

      if (do0) {
        f32x16 sc0 = {}, sc1 = {};
        __builtin_amdgcn_s_setprio(1);
#pragma unroll
        for (int f = 0; f < 4; ++f) {
          bf16x8 kf = lds_read_swK(Kb, kp * 64 + ql, f * 16 + hi5 * 8);
          sc0 = __builtin_amdgcn_mfma_f32_32x32x16_bf16(kf, qf[f], sc0, 0, 0, 0);
        }
        if (do1) {
#pragma unroll
          for (int f = 0; f < 4; ++f) {
            bf16x8 kf = lds_read_swK(Kb, kp * 64 + 32 + ql, f * 16 + hi5 * 8);
            sc1 = __builtin_amdgcn_mfma_f32_32x32x16_bf16(kf, qf[f], sc1, 0, 0, 0);
          }
        }
        __builtin_amdgcn_s_setprio(0);

        if (part0) {
#pragma unroll
          for (int g = 0; g < 16; ++g) {
            int kvg = kv0w + (g & 3) + 8 * (g >> 2) + 4 * hi5;
            if (kvg > qglob) sc0[g] = -1e30f;
          }
        }
        if (do1 && part1) {
#pragma unroll
          for (int g = 0; g < 16; ++g) {
            int kvg = kv0w + 32 + (g & 3) + 8 * (g >> 2) + 4 * hi5;
            if (kvg > qglob) sc1[g] = -1e30f;
          }
        }

        float pm = sc0[0];
#pragma unroll
        for (int g = 1; g < 16; ++g) pm = fmaxf(pm, sc0[g]);
        if (do1) {
#pragma unroll
          for (int g = 0; g < 16; ++g) pm = fmaxf(pm, sc1[g]);
        }
        pm = fmaxf(pm, __shfl_xor(pm, 32));

        if (!__all(pm - m_r <= 8.0f)) {
          float mnew = fmaxf(m_r, pm);
          float scl = __builtin_exp2f(m_r - mnew);
          l_r *= scl;
#pragma unroll
          for (int g = 0; g < 16; ++g) { out0[g] *= scl; out1[g] *= scl; }
          m_r = mnew;
        }

        float l_add = 0.f;
#define PV_CHUNK(SVEC, HALF, C)                                                \
        {                                                                      \
          const int g0 = (HALF) * 8;                                           \
          float p0 = __builtin_exp2f((SVEC)[g0 + 0] - m_r);                    \
          float p1 = __builtin_exp2f((SVEC)[g0 + 1] - m_r);                    \
          float p2 = __builtin_exp2f((SVEC)[g0 + 2] - m_r);                    \
          float p3 = __builtin_exp2f((SVEC)[g0 + 3] - m_r);                    \
          float p4 = __builtin_exp2f((SVEC)[g0 + 4] - m_r);                    \
          float p5 = __builtin_exp2f((SVEC)[g0 + 5] - m_r);                    \
          float p6 = __builtin_exp2f((SVEC)[g0 + 6] - m_r);                    \
          float p7 = __builtin_exp2f((SVEC)[g0 + 7] - m_r);                    \
          l_add += ((p0 + p1) + (p2 + p3)) + ((p4 + p5) + (p6 + p7));          \
          unsigned int u0 = cvt_pk_bf16(p0, p1);                               \
          unsigned int u1 = cvt_pk_bf16(p2, p3);                               \
          unsigned int u2 = cvt_pk_bf16(p4, p5);                               \
          unsigned int u3 = cvt_pk_bf16(p6, p7);                               \
          unsigned int ta = hi5 ? u0 : u2, tb = hi5 ? u1 : u3;                 \
          unsigned int ra = (unsigned int)__shfl_xor((int)ta, 32);             \
          unsigned int rb = (unsigned int)__shfl_xor((int)tb, 32);             \
          u32x4 pw = {hi5 ? ra : u0, hi5 ? rb : u1,                            \
                      hi5 ? u2 : ra, hi5 ? u3 : rb};                           \
          bf16x8 pf = __builtin_bit_cast(bf16x8, pw);                          \
          bf16x8 vf0 = lds_read_swV(Vb, ql, kp * 64 + (C) * 16 + hi5 * 8);     \
          out0 = __builtin_amdgcn_mfma_f32_32x32x16_bf16(vf0, pf, out0, 0, 0, 0);\
          bf16x8 vf1 = lds_read_swV(Vb, 32 + ql, kp * 64 + (C) * 16 + hi5 * 8);\
          out1 = __builtin_amdgcn_mfma_f32_32x32x16_bf16(vf1, pf, out1, 0, 0, 0);\
        }
        __builtin_amdgcn_s_setprio(1);
        PV_CHUNK(sc0, 0, 0);
        PV_CHUNK(sc0, 1, 1);
        if (do1) {
          PV_CHUNK(sc1, 0, 2);
          PV_CHUNK(sc1, 1, 3);
        }
        __builtin_amdgcn_s_setprio(0);
#undef PV_CHUNK

        l_add += __shfl_xor(l_add, 32);
        l_r += l_add;
      }
      __syncthreads();   // publishes prefetched buffer; frees current
    }

    // ---- merge partials across kv-parity (scratch overlays buffer 0) ----
    float* scr = (float*)smem;   // [qh][lane][34]: out0[16], out1[16], m, l
    if (kp == 1) {
      float* p = scr + ((size_t)qh * 64 + lane) * 34;
#pragma unroll
      for (int g = 0; g < 16; ++g) { p[g] = out0[g]; p[16 + g] = out1[g]; }
      p[32] = m_r;
      p[33] = l_r;
    }
    __syncthreads();
    if (kp == 0) {
      const float* p = scr + ((size_t)qh * 64 + lane) * 34;
      float m1 = p[32], l1 = p[33];
      float mM = fmaxf(m_r, m1);
      float s0 = __builtin_exp2f(m_r - mM);
      float s1 = __builtin_exp2f(m1 - mM);
      float rcp = 1.0f / (l_r * s0 + l1 * s1);
      float a0 = s0 * rcp, a1 = s1 * rcp;
      unsigned short* orow = Op + basebs + (size_t)qglob * D_ + hoff;
#pragma unroll
      for (int i = 0; i < 4; ++i) {
        u32x2 o0 = {cvt_pk_bf16(out0[4 * i + 0] * a0 + p[4 * i + 0] * a1,
                                out0[4 * i + 1] * a0 + p[4 * i + 1] * a1),
                    cvt_pk_bf16(out0[4 * i + 2] * a0 + p[4 * i + 2] * a1,
                                out0[4 * i + 3] * a0 + p[4 * i + 3] * a1)};
        *(u32x2*)(orow + 8 * i + 4 * hi5) = o0;
        u32x2 o1 = {cvt_pk_bf16(out1[4 * i + 0] * a0 + p[16 + 4 * i + 0] * a1,
                                out1[4 * i + 1] * a0 + p[16 + 4 * i + 1] * a1),
                    cvt_pk_bf16(out1[4 * i + 2] * a0 + p[16 + 4 * i + 2] * a1,
                                out1[4 * i + 3] * a0 + p[16 + 4 * i + 3] * a1)};
        *(u32x2*)(orow + 32 + 8 * i + 4 * hi5) = o1;
      }
    }
    __syncthreads();   // scratch reads done before next tile stages buffer 0
  }
#undef STAGE
}

// ---------------------------- launch ---------------------------------------
extern "C" void kernel_launch(void* const* d_in, const int* in_sizes, int n_in,
                              void* d_out, int out_size, void* d_ws, size_t ws_size,
                              hipStream_t stream) {
  const float* q  = (const float*)d_in[0];
  const float* k  = (const float*)d_in[1];
  const float* v  = (const float*)d_in[2];
  // d_in[3] = causal mask (tril) -- semantics hard-coded in flash_attn
  const float* Wq = (const float*)d_in[4];
  const float* bq = (const float*)d_in[5];
  const float* Wk = (const float*)d_in[6];
  const float* bk = (const float*)d_in[7];
  const float* Wv = (const float*)d_in[8];
  const float* bv = (const float*)d_in[9];
  const float* Wo = (const float*)d_in[10];
  const float* bo = (const float*)d_in[11];

  const int MSD = B_ * S_;     // 4096 rows
  unsigned short* ws = (unsigned short*)d_ws;
  unsigned short* Xq  = ws;
  unsigned short* Xk  = Xq  + (size_t)MSD * D_;
  unsigned short* Xv  = Xk  + (size_t)MSD * D_;
  unsigned short* Wqb = Xv  + (size_t)MSD * D_;
  unsigned short* Wkb = Wqb + (size_t)D_ * D_;
  unsigned short* Wvb = Wkb + (size_t)D_ * D_;
  unsigned short* Wob = Wvb + (size_t)D_ * D_;
  unsigned short* Qp  = Wob + (size_t)D_ * D_;
  unsigned short* Kp  = Qp  + (size_t)MSD * D_;
  unsigned short* Vt  = Kp  + (size_t)MSD * D_;   // V^T per head: [b][h][dk][s]
  unsigned short* At  = Vt  + (size_t)MSD * D_;

  const int n4a = MSD * D_ / 4;   // 1048576
  const int n4w = D_ * D_ / 4;    // 262144
  dim3 g3(n4a / 256, 3);
  cvt3<<<g3, 256, 0, stream>>>(q, k, v, Xq, Xk, Xv);
  dim3 g4(n4w / 256, 4);
  cvt4<<<g4, 256, 0, stream>>>(Wq, Wk, Wv, Wo, Wqb, Wkb, Wvb, Wob);

  dim3 gqkv(MSD / 128, D_ / 128, 3);   // (32, 8, 3) = 768 blocks
  gemm_qkv<<<gqkv, 256, 0, stream>>>(Xq, Xk, Xv, Wqb, Wkb, Wvb,
                                     bq, bk, bv, Qp, Kp, Vt);

  dim3 ga(16, H_, B_);                 // 512 uniform blocks
  flash_attn<<<ga, 256, 0, stream>>>(Qp, Kp, Vt, At);

  dim3 go(MSD / 64, D_ / 128);         // (64, 8) = 512 blocks
  gemm_o<<<go, 256, 0, stream>>>(At, Wob, bo, (float*)d_out, MSD, D_, D_);
}

// Round 10
// 131.275 us; speedup vs baseline: 1.2914x; 1.0550x over previous
//
#include <hip/hip_runtime.h>
#include <hip/hip_bf16.h>
#include <cstdint>
#include <cstddef>

// ---------------------------------------------------------------------------
// MultiHeadAttention (B=2, S=2048, D=1024, H=16, DK=64), fp32 in/out,
// bf16 MFMA internal compute.
// cvt(2 fused) -> QKV GEMM (grid.z; XOR-swizzled LDS, Q pre-scaled log2e/8;
// V^T per head) -> flash attention (paired q-tiles, dbuf rounds, in-reg P,
// defer-max, partial merge) -> O GEMM 64x128 (XOR-swizzled LDS, fp32 out)
// ---------------------------------------------------------------------------

#define B_ 2
#define S_ 2048
#define D_ 1024
#define H_ 16
#define DK_ 64
#define QSCALE 0.1803368801111244f   /* (1/8)*log2(e): softmax in exp2 domain */

typedef __attribute__((ext_vector_type(8))) short bf16x8;
typedef __attribute__((ext_vector_type(4))) float f32x4;
typedef __attribute__((ext_vector_type(16))) float f32x16;
typedef __attribute__((ext_vector_type(4))) unsigned short u16x4;
typedef __attribute__((ext_vector_type(4))) float float4v;
typedef __attribute__((ext_vector_type(2))) unsigned int u32x2;
typedef __attribute__((ext_vector_type(4))) unsigned int u32x4;

__device__ __forceinline__ unsigned short f2bf(float f) {
  unsigned int u = __float_as_uint(f);
  u += 0x7FFFu + ((u >> 16) & 1u);
  return (unsigned short)(u >> 16);
}
__device__ __forceinline__ unsigned int cvt_pk_bf16(float lo, float hi) {
  unsigned int r;
  asm("v_cvt_pk_bf16_f32 %0, %1, %2" : "=v"(r) : "v"(lo), "v"(hi));
  return r;
}
// swizzled read of a [R][64]-ushort LDS tile (128B rows): byte ^= ((row&7)<<4)
__device__ __forceinline__ bf16x8 lds_read_sw64(const unsigned short* base, int row, int col) {
  int P = (row * 64 + col) * 2;
  int X = P ^ ((row & 7) << 4);
  return *(const bf16x8*)((const char*)base + X);
}

// ---------------------------- fp32 -> bf16 converts ------------------------
__global__ __launch_bounds__(256) void cvt3(const float* __restrict__ s0,
                                            const float* __restrict__ s1,
                                            const float* __restrict__ s2,
                                            unsigned short* __restrict__ d0,
                                            unsigned short* __restrict__ d1,
                                            unsigned short* __restrict__ d2) {
  const float* src = blockIdx.y == 0 ? s0 : blockIdx.y == 1 ? s1 : s2;
  unsigned short* dst = blockIdx.y == 0 ? d0 : blockIdx.y == 1 ? d1 : d2;
  int i = blockIdx.x * 256 + threadIdx.x;
  float4v v = *(const float4v*)(src + (size_t)i * 4);
  u16x4 o;
  o[0] = f2bf(v[0]); o[1] = f2bf(v[1]); o[2] = f2bf(v[2]); o[3] = f2bf(v[3]);
  *(u16x4*)(dst + (size_t)i * 4) = o;
}

__global__ __launch_bounds__(256) void cvt4(const float* __restrict__ s0,
                                            const float* __restrict__ s1,
                                            const float* __restrict__ s2,
                                            const float* __restrict__ s3,
                                            unsigned short* __restrict__ d0,
                                            unsigned short* __restrict__ d1,
                                            unsigned short* __restrict__ d2,
                                            unsigned short* __restrict__ d3) {
  int z = blockIdx.y;
  const float* src = z == 0 ? s0 : z == 1 ? s1 : z == 2 ? s2 : s3;
  unsigned short* dst = z == 0 ? d0 : z == 1 ? d1 : z == 2 ? d2 : d3;
  int i = blockIdx.x * 256 + threadIdx.x;
  float4v v = *(const float4v*)(src + (size_t)i * 4);
  u16x4 o;
  o[0] = f2bf(v[0]); o[1] = f2bf(v[1]); o[2] = f2bf(v[2]); o[3] = f2bf(v[3]);
  *(u16x4*)(dst + (size_t)i * 4) = o;
}

// ---------------------------- fused QKV GEMM -------------------------------
// XOR-swizzled LDS staging: dest byte X = tid*16 + i*4096 (linear, lane-
// ordered); logical byte P = X ^ (((X>>7)&7)<<4) -> source row/col. Reads
// use lds_read_sw64. Eliminates the 16-way row-stride-128B bank conflict.
__global__ __launch_bounds__(256) void gemm_qkv(
    const unsigned short* __restrict__ Xq, const unsigned short* __restrict__ Xk,
    const unsigned short* __restrict__ Xv, const unsigned short* __restrict__ Wq,
    const unsigned short* __restrict__ Wk, const unsigned short* __restrict__ Wv,
    const float* __restrict__ bq, const float* __restrict__ bk,
    const float* __restrict__ bv, unsigned short* __restrict__ Qp,
    unsigned short* __restrict__ Kp, unsigned short* __restrict__ Vt) {
  const int z = blockIdx.z;
  const unsigned short* A = z == 0 ? Xq : z == 1 ? Xk : Xv;
  const unsigned short* W = z == 0 ? Wq : z == 1 ? Wk : Wv;
  const float* bias = z == 0 ? bq : z == 1 ? bk : bv;
  const int K = D_, N = D_;

  __shared__ __align__(16) unsigned short As[128 * 64];
  __shared__ __align__(16) unsigned short Bs[128 * 64];
  const int tid  = threadIdx.x;
  const int lane = tid & 63;
  const int m0 = blockIdx.x * 128;
  const int n0 = blockIdx.y * 128;
  const int wr = ((tid >> 6) >> 1) * 64;
  const int wc = ((tid >> 6) & 1) * 64;
  const int lr = lane & 15;
  const int lk = (lane >> 4) * 8;
  f32x4 acc[4][4] = {};

  // swizzled staging addresses (hoisted)
  int dstX[4], srow[4], scolu[4];
#pragma unroll
  for (int i = 0; i < 4; ++i) {
    int X = tid * 16 + i * 4096;
    int P = X ^ (((X >> 7) & 7) << 4);
    dstX[i] = X;
    srow[i] = P >> 7;
    scolu[i] = (P & 127) >> 1;
  }

  for (int k0 = 0; k0 < K; k0 += 64) {
    __syncthreads();
#pragma unroll
    for (int i = 0; i < 4; ++i) {
      const unsigned short* gA = A + (size_t)(m0 + srow[i]) * K + k0 + scolu[i];
      const unsigned short* gB = W + (size_t)(n0 + srow[i]) * K + k0 + scolu[i];
      __builtin_amdgcn_global_load_lds((const __attribute__((address_space(1))) void*)gA,
          (__attribute__((address_space(3))) void*)((char*)As + dstX[i]), 16, 0, 0);
      __builtin_amdgcn_global_load_lds((const __attribute__((address_space(1))) void*)gB,
          (__attribute__((address_space(3))) void*)((char*)Bs + dstX[i]), 16, 0, 0);
    }
    __syncthreads();
#pragma unroll
    for (int kk = 0; kk < 2; ++kk) {
      bf16x8 a[4], b[4];
#pragma unroll
      for (int m = 0; m < 4; ++m)
        a[m] = lds_read_sw64(As, wr + m * 16 + lr, kk * 32 + lk);
#pragma unroll
      for (int n = 0; n < 4; ++n)
        b[n] = lds_read_sw64(Bs, wc + n * 16 + lr, kk * 32 + lk);
#pragma unroll
      for (int m = 0; m < 4; ++m)
#pragma unroll
        for (int n = 0; n < 4; ++n)
          acc[m][n] = __builtin_amdgcn_mfma_f32_16x16x32_bf16(a[m], b[n], acc[m][n], 0, 0, 0);
    }
  }

  const int rbase = (lane >> 4) * 4;
  if (z == 2) {
#pragma unroll
    for (int m = 0; m < 4; ++m)
#pragma unroll
      for (int n = 0; n < 4; ++n) {
        int col = n0 + wc + n * 16 + lr;
        float bvv = bias[col];
        int row0 = m0 + wr + m * 16 + rbase;
        int bb = row0 >> 11, s = row0 & 2047;
        int h = col >> 6, dk = col & 63;
        u16x4 o;
#pragma unroll
        for (int r = 0; r < 4; ++r) o[r] = f2bf(acc[m][n][r] + bvv);
        size_t idx = (((size_t)bb * H_ + h) * DK_ + dk) * S_ + s;
        *(u16x4*)(Vt + idx) = o;
      }
  } else {
    unsigned short* Cout = z == 0 ? Qp : Kp;
    const float scale = z == 0 ? QSCALE : 1.0f;
#pragma unroll
    for (int m = 0; m < 4; ++m)
#pragma unroll
      for (int n = 0; n < 4; ++n) {
        int col = n0 + wc + n * 16 + lr;
        float bvv = bias[col];
#pragma unroll
        for (int r = 0; r < 4; ++r) {
          int row = m0 + wr + m * 16 + rbase + r;
          Cout[(size_t)row * N + col] = f2bf((acc[m][n][r] + bvv) * scale);
        }
      }
  }
}

// ---------------------------- O GEMM (64x128 tile) -------------------------
__global__ __launch_bounds__(256) void gemm_o(const unsigned short* __restrict__ A,
                                              const unsigned short* __restrict__ W,
                                              const float* __restrict__ bias,
                                              float* __restrict__ C,
                                              int M, int N, int K) {
  __shared__ __align__(16) unsigned short As[64 * 64];
  __shared__ __align__(16) unsigned short Bs[128 * 64];
  const int tid  = threadIdx.x;
  const int lane = tid & 63;
  const int m0 = blockIdx.x * 64;
  const int n0 = blockIdx.y * 128;
  const int wr = ((tid >> 6) >> 1) * 32;
  const int wc = ((tid >> 6) & 1) * 64;
  const int lr = lane & 15;
  const int lk = (lane >> 4) * 8;
  f32x4 acc[2][4] = {};

  int dstX[4], srow[4], scolu[4];
#pragma unroll
  for (int i = 0; i < 4; ++i) {
    int X = tid * 16 + i * 4096;
    int P = X ^ (((X >> 7) & 7) << 4);
    dstX[i] = X;
    srow[i] = P >> 7;
    scolu[i] = (P & 127) >> 1;
  }

  for (int k0 = 0; k0 < K; k0 += 64) {
    __syncthreads();
#pragma unroll
    for (int i = 0; i < 2; ++i) {
      const unsigned short* gA = A + (size_t)(m0 + srow[i]) * K + k0 + scolu[i];
      __builtin_amdgcn_global_load_lds((const __attribute__((address_space(1))) void*)gA,
          (__attribute__((address_space(3))) void*)((char*)As + dstX[i]), 16, 0, 0);
    }
#pragma unroll
    for (int i = 0; i < 4; ++i) {
      const unsigned short* gB = W + (size_t)(n0 + srow[i]) * K + k0 + scolu[i];
      __builtin_amdgcn_global_load_lds((const __attribute__((address_space(1))) void*)gB,
          (__attribute__((address_space(3))) void*)((char*)Bs + dstX[i]), 16, 0, 0);
    }
    __syncthreads();
#pragma unroll
    for (int kk = 0; kk < 2; ++kk) {
      bf16x8 a[2], b[4];
#pragma unroll
      for (int m = 0; m < 2; ++m)
        a[m] = lds_read_sw64(As, wr + m * 16 + lr, kk * 32 + lk);
#pragma unroll
      for (int n = 0; n < 4; ++n)
        b[n] = lds_read_sw64(Bs, wc + n * 16 + lr, kk * 32 + lk);
#pragma unroll
      for (int m = 0; m < 2; ++m)
#pragma unroll
        for (int n = 0; n < 4; ++n)
          acc[m][n] = __builtin_amdgcn_mfma_f32_16x16x32_bf16(a[m], b[n], acc[m][n], 0, 0, 0);
    }
  }

  const int rbase = (lane >> 4) * 4;
#pragma unroll
  for (int m = 0; m < 2; ++m)
#pragma unroll
    for (int n = 0; n < 4; ++n) {
      int col = n0 + wc + n * 16 + lr;
      float bvv = bias[col];
#pragma unroll
      for (int r = 0; r < 4; ++r) {
        int row = m0 + wr + m * 16 + rbase + r;
        C[(size_t)row * N + col] = acc[m][n][r] + bvv;
      }
    }
}

// ---------------------------- flash attention ------------------------------
// Grid: (16, H, B). Block processes q-tiles qtA=31-bx then qtB=bx (uniform
// 17 rounds total). 4 waves: qh=w&1 (32 q rows), kp=w>>1 (64-kv half of each
// 128-kv round). Double-buffered rounds: barrier -> prefetch(r+1) ->
// compute(r) -> barrier. Partials merged across kp via LDS scratch overlay.
__device__ __forceinline__ bf16x8 lds_read_swK(const unsigned short* base, int row, int col) {
  int P = (row * 64 + col) * 2;
  int X = P ^ ((row & 7) << 4);
  return *(const bf16x8*)((const char*)base + X);
}
__device__ __forceinline__ bf16x8 lds_read_swV(const unsigned short* base, int row, int col) {
  int P = (row * 128 + col) * 2;
  int X = P ^ ((row & 7) << 4);
  return *(const bf16x8*)((const char*)base + X);
}

__global__ __launch_bounds__(256) void flash_attn(const unsigned short* __restrict__ Qp,
                                                  const unsigned short* __restrict__ Kp,
                                                  const unsigned short* __restrict__ Vtp,
                                                  unsigned short* __restrict__ Op) {
  __shared__ __align__(16) unsigned short smem[32768];

  const int tid  = threadIdx.x;
  const int lane = tid & 63;
  const int w = tid >> 6;
  const int qh = w & 1;         // q half (32 rows)
  const int kp = w >> 1;        // kv parity (which 64 of the 128-round)
  const int h  = blockIdx.y;
  const int b  = blockIdx.z;
  const int ql = lane & 31;
  const int hi5 = lane >> 5;
  const size_t basebs = (size_t)b * S_ * D_;
  const int hoff = h * DK_;

  const unsigned short* gK0 = Kp + basebs + hoff;
  const unsigned short* gV0 = Vtp + ((size_t)b * H_ + h) * DK_ * S_;

  int dstXK[4], srcK[4], srcV[4];
#pragma unroll
  for (int i = 0; i < 4; ++i) {
    int X = tid * 16 + i * 4096;
    int Pk = X ^ (((X >> 7) & 7) << 4);          // K: 128B rows
    dstXK[i] = X;
    srcK[i] = (Pk >> 7) * D_ + ((Pk & 127) >> 1);
    int Pv = X ^ (((X >> 8) & 7) << 4);          // V: 256B rows
    srcV[i] = (Pv >> 8) * S_ + ((Pv & 255) >> 1);
  }

#define STAGE(RR, BUF)                                                         \
  {                                                                            \
    const unsigned short* gK = gK0 + (size_t)((RR) * 128) * D_;                \
    const unsigned short* gV = gV0 + (RR) * 128;                               \
    char* kb = (char*)smem + (BUF) * 32768;                                    \
    char* vb = kb + 16384;                                                     \
    _Pragma("unroll")                                                          \
    for (int i = 0; i < 4; ++i) {                                              \
      __builtin_amdgcn_global_load_lds(                                        \
          (const __attribute__((address_space(1))) void*)(gK + srcK[i]),       \
          (__attribute__((address_space(3))) void*)(kb + dstXK[i]), 16, 0, 0); \
      __builtin_amdgcn_global_load_lds(                                        \
          (const __attribute__((address_space(1))) void*)(gV + srcV[i]),       \
          (__attribute__((address_space(3))) void*)(vb + dstXK[i]), 16, 0, 0); \
    }                                                                          \
  }

  for (int s = 0; s < 2; ++s) {
    const int qt = s == 0 ? 31 - (int)blockIdx.x : (int)blockIdx.x;
    const int q0 = qt * 64;
    const int qbase = q0 + qh * 32;
    const int qglob = qbase + ql;

    bf16x8 qf[4];
    {
      const unsigned short* qrow = Qp + basebs + (size_t)qglob * D_ + hoff;
#pragma unroll
      for (int f = 0; f < 4; ++f)
        qf[f] = *(const bf16x8*)(qrow + f * 16 + hi5 * 8);
    }

    float m_r = -1e30f;
    float l_r = 0.f;
    f32x16 out0 = {};   // d-tile 0: d = (reg&3)+8*(reg>>2)+4*hi5
    f32x16 out1 = {};   // d-tile 1: d = 32 + same

    const int R = (qt + 2) >> 1;   // rounds of 128 kv

    STAGE(0, 0);
    __syncthreads();               // round 0 staged

    for (int r = 0; r < R; ++r) {
      const int cur = r & 1;
      if (r + 1 < R) STAGE(r + 1, cur ^ 1);   // prefetch, hidden under compute

      const unsigned short* Kb = smem + cur * 16384;
      const unsigned short* Vb = Kb + 8192;

      const int kv0w = r * 128 + kp * 64;
      const bool do0 = (kv0w <= qbase);
      const bool do1 = (kv0w + 32 <= qbase);
      const bool part0 = (kv0w == qbase);
      const bool part1 = (kv0w + 32 == qbase);

      if (do0) {
        f32x16 sc0 = {}, sc1 = {};
        __builtin_amdgcn_s_setprio(1);
#pragma unroll
        for (int f = 0; f < 4; ++f) {
          bf16x8 kf = lds_read_swK(Kb, kp * 64 + ql, f * 16 + hi5 * 8);
          sc0 = __builtin_amdgcn_mfma_f32_32x32x16_bf16(kf, qf[f], sc0, 0, 0, 0);
        }
        if (do1) {
#pragma unroll
          for (int f = 0; f < 4; ++f) {
            bf16x8 kf = lds_read_swK(Kb, kp * 64 + 32 + ql, f * 16 + hi5 * 8);
            sc1 = __builtin_amdgcn_mfma_f32_32x32x16_bf16(kf, qf[f], sc1, 0, 0, 0);
          }
        }
        __builtin_amdgcn_s_setprio(0);

        if (part0) {
#pragma unroll
          for (int g = 0; g < 16; ++g) {
            int kvg = kv0w + (g & 3) + 8 * (g >> 2) + 4 * hi5;
            if (kvg > qglob) sc0[g] = -1e30f;
          }
        }
        if (do1 && part1) {
#pragma unroll
          for (int g = 0; g < 16; ++g) {
            int kvg = kv0w + 32 + (g & 3) + 8 * (g >> 2) + 4 * hi5;
            if (kvg > qglob) sc1[g] = -1e30f;
          }
        }

        float pm = sc0[0];
#pragma unroll
        for (int g = 1; g < 16; ++g) pm = fmaxf(pm, sc0[g]);
        if (do1) {
#pragma unroll
          for (int g = 0; g < 16; ++g) pm = fmaxf(pm, sc1[g]);
        }
        pm = fmaxf(pm, __shfl_xor(pm, 32));

        if (!__all(pm - m_r <= 8.0f)) {
          float mnew = fmaxf(m_r, pm);
          float scl = __builtin_exp2f(m_r - mnew);
          l_r *= scl;
#pragma unroll
          for (int g = 0; g < 16; ++g) { out0[g] *= scl; out1[g] *= scl; }
          m_r = mnew;
        }

        float l_add = 0.f;
#define PV_CHUNK(SVEC, HALF, C)                                                \
        {                                                                      \
          const int g0 = (HALF) * 8;                                           \
          float p0 = __builtin_exp2f((SVEC)[g0 + 0] - m_r);                    \
          float p1 = __builtin_exp2f((SVEC)[g0 + 1] - m_r);                    \
          float p2 = __builtin_exp2f((SVEC)[g0 + 2] - m_r);                    \
          float p3 = __builtin_exp2f((SVEC)[g0 + 3] - m_r);                    \
          float p4 = __builtin_exp2f((SVEC)[g0 + 4] - m_r);                    \
          float p5 = __builtin_exp2f((SVEC)[g0 + 5] - m_r);                    \
          float p6 = __builtin_exp2f((SVEC)[g0 + 6] - m_r);                    \
          float p7 = __builtin_exp2f((SVEC)[g0 + 7] - m_r);                    \
          l_add += ((p0 + p1) + (p2 + p3)) + ((p4 + p5) + (p6 + p7));          \
          unsigned int u0 = cvt_pk_bf16(p0, p1);                               \
          unsigned int u1 = cvt_pk_bf16(p2, p3);                               \
          unsigned int u2 = cvt_pk_bf16(p4, p5);                               \
          unsigned int u3 = cvt_pk_bf16(p6, p7);                               \
          unsigned int ta = hi5 ? u0 : u2, tb = hi5 ? u1 : u3;                 \
          unsigned int ra = (unsigned int)__shfl_xor((int)ta, 32);             \
          unsigned int rb = (unsigned int)__shfl_xor((int)tb, 32);             \
          u32x4 pw = {hi5 ? ra : u0, hi5 ? rb : u1,                            \
                      hi5 ? u2 : ra, hi5 ? u3 : rb};                           \
          bf16x8 pf = __builtin_bit_cast(bf16x8, pw);                          \
          bf16x8 vf0 = lds_read_swV(Vb, ql, kp * 64 + (C) * 16 + hi5 * 8);     \
          out0 = __builtin_amdgcn_mfma_f32_32x32x16_bf16(vf0, pf, out0, 0, 0, 0);\
          bf16x8 vf1 = lds_read_swV(Vb, 32 + ql, kp * 64 + (C) * 16 + hi5 * 8);\
          out1 = __builtin_amdgcn_mfma_f32_32x32x16_bf16(vf1, pf, out1, 0, 0, 0);\
        }
        __builtin_amdgcn_s_setprio(1);
        PV_CHUNK(sc0, 0, 0);
        PV_CHUNK(sc0, 1, 1);
        if (do1) {
          PV_CHUNK(sc1, 0, 2);
          PV_CHUNK(sc1, 1, 3);
        }
        __builtin_amdgcn_s_setprio(0);
#undef PV_CHUNK

        l_add += __shfl_xor(l_add, 32);
        l_r += l_add;
      }
      __syncthreads();   // publishes prefetched buffer; frees current
    }

    // ---- merge partials across kv-parity (scratch overlays buffer 0) ----
    float* scr = (float*)smem;   // [qh][lane][34]: out0[16], out1[16], m, l
    if (kp == 1) {
      float* p = scr + ((size_t)qh * 64 + lane) * 34;
#pragma unroll
      for (int g = 0; g < 16; ++g) { p[g] = out0[g]; p[16 + g] = out1[g]; }
      p[32] = m_r;
      p[33] = l_r;
    }
    __syncthreads();
    if (kp == 0) {
      const float* p = scr + ((size_t)qh * 64 + lane) * 34;
      float m1 = p[32], l1 = p[33];
      float mM = fmaxf(m_r, m1);
      float s0 = __builtin_exp2f(m_r - mM);
      float s1 = __builtin_exp2f(m1 - mM);
      float rcp = 1.0f / (l_r * s0 + l1 * s1);
      float a0 = s0 * rcp, a1 = s1 * rcp;
      unsigned short* orow = Op + basebs + (size_t)qglob * D_ + hoff;
#pragma unroll
      for (int i = 0; i < 4; ++i) {
        u32x2 o0 = {cvt_pk_bf16(out0[4 * i + 0] * a0 + p[4 * i + 0] * a1,
                                out0[4 * i + 1] * a0 + p[4 * i + 1] * a1),
                    cvt_pk_bf16(out0[4 * i + 2] * a0 + p[4 * i + 2] * a1,
                                out0[4 * i + 3] * a0 + p[4 * i + 3] * a1)};
        *(u32x2*)(orow + 8 * i + 4 * hi5) = o0;
        u32x2 o1 = {cvt_pk_bf16(out1[4 * i + 0] * a0 + p[16 + 4 * i + 0] * a1,
                                out1[4 * i + 1] * a0 + p[16 + 4 * i + 1] * a1),
                    cvt_pk_bf16(out1[4 * i + 2] * a0 + p[16 + 4 * i + 2] * a1,
                                out1[4 * i + 3] * a0 + p[16 + 4 * i + 3] * a1)};
        *(u32x2*)(orow + 32 + 8 * i + 4 * hi5) = o1;
      }
    }
    __syncthreads();   // scratch reads done before next tile stages buffer 0
  }
#undef STAGE
}

// ---------------------------- launch ---------------------------------------
extern "C" void kernel_launch(void* const* d_in, const int* in_sizes, int n_in,
                              void* d_out, int out_size, void* d_ws, size_t ws_size,
                              hipStream_t stream) {
  const float* q  = (const float*)d_in[0];
  const float* k  = (const float*)d_in[1];
  const float* v  = (const float*)d_in[2];
  // d_in[3] = causal mask (tril) -- semantics hard-coded in flash_attn
  const float* Wq = (const float*)d_in[4];
  const float* bq = (const float*)d_in[5];
  const float* Wk = (const float*)d_in[6];
  const float* bk = (const float*)d_in[7];
  const float* Wv = (const float*)d_in[8];
  const float* bv = (const float*)d_in[9];
  const float* Wo = (const float*)d_in[10];
  const float* bo = (const float*)d_in[11];

  const int MSD = B_ * S_;     // 4096 rows
  unsigned short* ws = (unsigned short*)d_ws;
  unsigned short* Xq  = ws;
  unsigned short* Xk  = Xq  + (size_t)MSD * D_;
  unsigned short* Xv  = Xk  + (size_t)MSD * D_;
  unsigned short* Wqb = Xv  + (size_t)MSD * D_;
  unsigned short* Wkb = Wqb + (size_t)D_ * D_;
  unsigned short* Wvb = Wkb + (size_t)D_ * D_;
  unsigned short* Wob = Wvb + (size_t)D_ * D_;
  unsigned short* Qp  = Wob + (size_t)D_ * D_;
  unsigned short* Kp  = Qp  + (size_t)MSD * D_;
  unsigned short* Vt  = Kp  + (size_t)MSD * D_;   // V^T per head: [b][h][dk][s]
  unsigned short* At  = Vt  + (size_t)MSD * D_;

  const int n4a = MSD * D_ / 4;   // 1048576
  const int n4w = D_ * D_ / 4;    // 262144
  dim3 g3(n4a / 256, 3);
  cvt3<<<g3, 256, 0, stream>>>(q, k, v, Xq, Xk, Xv);
  dim3 g4(n4w / 256, 4);
  cvt4<<<g4, 256, 0, stream>>>(Wq, Wk, Wv, Wo, Wqb, Wkb, Wvb, Wob);

  dim3 gqkv(MSD / 128, D_ / 128, 3);   // (32, 8, 3) = 768 blocks
  gemm_qkv<<<gqkv, 256, 0, stream>>>(Xq, Xk, Xv, Wqb, Wkb, Wvb,
                                     bq, bk, bv, Qp, Kp, Vt);

  dim3 ga(16, H_, B_);                 // 512 uniform blocks
  flash_attn<<<ga, 256, 0, stream>>>(Qp, Kp, Vt, At);

  dim3 go(MSD / 64, D_ / 128);         // (64, 8) = 512 blocks
  gemm_o<<<go, 256, 0, stream>>>(At, Wob, bo, (float*)d_out, MSD, D_, D_);
}